// Round 1
// baseline (1207.253 us; speedup 1.0000x reference)
//
#include <hip/hip_runtime.h>
#include <hip/hip_bf16.h>

// GCN: 3x GCNConv(relu) + fc. N=50000 nodes, E=800000 edges, 512->96->96->96->64, fp32.
// Strategy r0: correctness-first. fp32 tiled GEMMs (no fp32 MFMA on CDNA4),
// scatter aggregation via native fp32 atomics (unsafeAtomicAdd -> global_atomic_add_f32).

constexpr int NN   = 50000;
constexpr int NE   = 800000;
constexpr int KIN  = 512;
constexpr int HIDD = 96;
constexpr int ODIM = 64;

__global__ void zero_kernel(float* __restrict__ p, int n) {
    int i = blockIdx.x * blockDim.x + threadIdx.x;
    if (i < n) p[i] = 0.0f;
}

__global__ void deg_kernel(const int* __restrict__ dst, float* __restrict__ deg) {
    int e = blockIdx.x * blockDim.x + threadIdx.x;
    if (e < NE) unsafeAtomicAdd(&deg[dst[e]], 1.0f);  // exact: integer-valued, < 2^24
}

__global__ void dinv_kernel(float* __restrict__ deg) {
    int i = blockIdx.x * blockDim.x + threadIdx.x;
    if (i < NN) deg[i] = 1.0f / sqrtf(deg[i] + 1.0f);  // precise rsqrt
}

// C[N,M] = A[N,K] @ W[K,M] (+bias) (+relu).  M in {96,64}, K % 16 == 0.
// Block: 256 threads = 16x16, 64 rows per block, TM = M/16 cols per thread.
template <int M, bool BIAS, bool RELU>
__launch_bounds__(256)
__global__ void gemm_kernel(const float* __restrict__ A, const float* __restrict__ W,
                            const float* __restrict__ bias, float* __restrict__ C,
                            int N, int K) {
    constexpr int KT = 16;
    constexpr int ROWS = 64;
    constexpr int TM = M / 16;
    __shared__ float sA[ROWS * KT];
    __shared__ float sW[KT * M];

    const int tid = threadIdx.x;
    const int tx = tid & 15;       // col group
    const int ty = tid >> 4;       // row group
    const int row0 = blockIdx.x * ROWS;

    float acc[4][TM];
#pragma unroll
    for (int i = 0; i < 4; ++i)
#pragma unroll
        for (int j = 0; j < TM; ++j) acc[i][j] = 0.0f;

    const int lr = tid >> 2;          // 0..63 tile row
    const int lc = (tid & 3) * 4;     // 0,4,8,12 tile col (float4)

    for (int k0 = 0; k0 < K; k0 += KT) {
        // stage A tile (64 x 16), float4 coalesced; contiguous LDS write (tid*4)
        int arow = row0 + lr;
        if (arow >= N) arow = N - 1;  // stores are guarded; clamped loads are discarded
        const float4 av = *(const float4*)(A + (size_t)arow * K + k0 + lc);
        *(float4*)(sA + lr * KT + lc) = av;
        // stage W tile (16 x M): contiguous chunk of W, coalesced
#pragma unroll
        for (int i = tid; i < KT * M; i += 256) sW[i] = W[k0 * M + i];
        __syncthreads();

#pragma unroll
        for (int kk = 0; kk < KT; ++kk) {
            float a[4];
#pragma unroll
            for (int i = 0; i < 4; ++i) a[i] = sA[(ty * 4 + i) * KT + kk];
            float w[TM];
#pragma unroll
            for (int j = 0; j < TM; ++j) w[j] = sW[kk * M + tx * TM + j];
#pragma unroll
            for (int i = 0; i < 4; ++i)
#pragma unroll
                for (int j = 0; j < TM; ++j) acc[i][j] = fmaf(a[i], w[j], acc[i][j]);
        }
        __syncthreads();
    }

#pragma unroll
    for (int i = 0; i < 4; ++i) {
        const int row = row0 + ty * 4 + i;
        if (row < N) {
#pragma unroll
            for (int j = 0; j < TM; ++j) {
                float v = acc[i][j];
                if (BIAS) v += bias[tx * TM + j];
                if (RELU) v = fmaxf(v, 0.0f);
                C[(size_t)row * M + tx * TM + j] = v;
            }
        }
    }
}

// agg[i,:] = h[i,:] * dinv[i]^2  (self-loop init; also fully initializes agg buffer)
__global__ void selfloop_kernel(const float* __restrict__ h, const float* __restrict__ dinv,
                                float* __restrict__ agg) {
    int t = blockIdx.x * blockDim.x + threadIdx.x;  // one float4 each
    constexpr int N4 = NN * HIDD / 4;
    if (t < N4) {
        const int node = (t * 4) / HIDD;
        const float di = dinv[node];
        const float s = di * di;
        float4 v = ((const float4*)h)[t];
        v.x *= s; v.y *= s; v.z *= s; v.w *= s;
        ((float4*)agg)[t] = v;
    }
}

// scatter: agg[dst,:] += h[src,:] * dinv[src]*dinv[dst].  192 thr = 2 edges x 96 feats.
__global__ void edge_kernel(const int* __restrict__ src, const int* __restrict__ dst,
                            const float* __restrict__ dinv, const float* __restrict__ h,
                            float* __restrict__ agg) {
    const int tid = threadIdx.x;
    const int e = blockIdx.x * 2 + tid / HIDD;
    const int f = tid % HIDD;
    if (e < NE) {
        const int s = src[e];
        const int d = dst[e];
        const float norm = dinv[s] * dinv[d];
        unsafeAtomicAdd(&agg[(size_t)d * HIDD + f], h[(size_t)s * HIDD + f] * norm);
    }
}

// out[i,:] = relu(agg[i,:] + b[:])
__global__ void biasrelu_kernel(const float* __restrict__ agg, const float* __restrict__ b,
                                float* __restrict__ out) {
    int t = blockIdx.x * blockDim.x + threadIdx.x;  // one float4 each
    constexpr int N4 = NN * HIDD / 4;
    if (t < N4) {
        const int f = (t * 4) % HIDD;
        float4 v = ((const float4*)agg)[t];
        v.x = fmaxf(v.x + b[f + 0], 0.0f);
        v.y = fmaxf(v.y + b[f + 1], 0.0f);
        v.z = fmaxf(v.z + b[f + 2], 0.0f);
        v.w = fmaxf(v.w + b[f + 3], 0.0f);
        ((float4*)out)[t] = v;
    }
}

extern "C" void kernel_launch(void* const* d_in, const int* in_sizes, int n_in,
                              void* d_out, int out_size, void* d_ws, size_t ws_size,
                              hipStream_t stream) {
    const float* x   = (const float*)d_in[0];
    const int*   ei  = (const int*)d_in[1];
    const float* W0  = (const float*)d_in[2];
    const float* b0  = (const float*)d_in[3];
    const float* W1  = (const float*)d_in[4];
    const float* b1  = (const float*)d_in[5];
    const float* W2  = (const float*)d_in[6];
    const float* b2  = (const float*)d_in[7];
    const float* fcW = (const float*)d_in[8];
    const float* fcb = (const float*)d_in[9];
    float* out = (float*)d_out;

    const int* src = ei;
    const int* dst = ei + NE;

    float* ws   = (float*)d_ws;
    float* dinv = ws;                      // [50000]
    float* bufA = ws + 50176;              // [NN*HIDD] = 4.8M floats
    float* bufB = bufA + (size_t)NN * HIDD;

    const int HN = NN * HIDD;          // 4.8M
    const int N4 = HN / 4;             // 1.2M

    dim3 b256(256);
    const int gN   = (NN + 255) / 256;
    const int gE   = (NE + 255) / 256;
    const int g4   = (N4 + 255) / 256;
    const int gGem = (NN + 63) / 64;       // 782
    const int gEdge = (NE + 1) / 2;        // 400000, 192 thr each

    // degrees -> dinv
    zero_kernel<<<gN, b256, 0, stream>>>(dinv, NN);
    deg_kernel<<<gE, b256, 0, stream>>>(dst, dinv);
    dinv_kernel<<<gN, b256, 0, stream>>>(dinv);

    // ---- layer 0: h = x @ W0 ; agg ; relu(+b0) ----
    gemm_kernel<HIDD, false, false><<<gGem, b256, 0, stream>>>(x, W0, nullptr, bufA, NN, KIN);
    selfloop_kernel<<<g4, b256, 0, stream>>>(bufA, dinv, bufB);
    edge_kernel<<<gEdge, dim3(192), 0, stream>>>(src, dst, dinv, bufA, bufB);
    biasrelu_kernel<<<g4, b256, 0, stream>>>(bufB, b0, bufA);

    // ---- layer 1 ----
    gemm_kernel<HIDD, false, false><<<gGem, b256, 0, stream>>>(bufA, W1, nullptr, bufB, NN, HIDD);
    selfloop_kernel<<<g4, b256, 0, stream>>>(bufB, dinv, bufA);
    edge_kernel<<<gEdge, dim3(192), 0, stream>>>(src, dst, dinv, bufB, bufA);
    biasrelu_kernel<<<g4, b256, 0, stream>>>(bufA, b1, bufB);

    // ---- layer 2 ----
    gemm_kernel<HIDD, false, false><<<gGem, b256, 0, stream>>>(bufB, W2, nullptr, bufA, NN, HIDD);
    selfloop_kernel<<<g4, b256, 0, stream>>>(bufA, dinv, bufB);
    edge_kernel<<<gEdge, dim3(192), 0, stream>>>(src, dst, dinv, bufA, bufB);
    biasrelu_kernel<<<g4, b256, 0, stream>>>(bufB, b2, bufA);

    // ---- fc: out = h @ fcW + fcb ----
    gemm_kernel<ODIM, true, false><<<gGem, b256, 0, stream>>>(bufA, fcW, fcb, out, NN, HIDD);
}

// Round 2
// 556.056 us; speedup vs baseline: 2.1711x; 2.1711x over previous
//
#include <hip/hip_runtime.h>
#include <hip/hip_bf16.h>

// GCN r2: CSR-by-dst gather-reduce replaces fp32 atomic scatter.
// Algebra: hs = h*dinv (fused into GEMM epilogue);
//          out = relu(dinv[i]*(sum_{e->i} hs[src_e] + hs[i]) + b)   (fused into gather)

constexpr int NN   = 50000;
constexpr int NE   = 800000;
constexpr int KIN  = 512;
constexpr int HIDD = 96;
constexpr int ODIM = 64;
constexpr int NBLK = (NN + 255) / 256;   // 196 scan blocks

__global__ void zero_int_kernel(int* __restrict__ p, int n) {
    int i = blockIdx.x * blockDim.x + threadIdx.x;
    if (i < n) p[i] = 0;
}

__global__ void hist_kernel(const int* __restrict__ dst, int* __restrict__ deg) {
    int e = blockIdx.x * blockDim.x + threadIdx.x;
    if (e < NE) atomicAdd(&deg[dst[e]], 1);
}

// Hillis-Steele inclusive scan of 256 per block; emits per-elem exclusive + block total.
__global__ void scan1_kernel(const int* __restrict__ deg, int* __restrict__ excl,
                             int* __restrict__ partials) {
    __shared__ int tmp[256];
    const int tid = threadIdx.x;
    const int i = blockIdx.x * 256 + tid;
    const int v = (i < NN) ? deg[i] : 0;
    tmp[tid] = v;
    __syncthreads();
#pragma unroll
    for (int off = 1; off < 256; off <<= 1) {
        int t = (tid >= off) ? tmp[tid - off] : 0;
        __syncthreads();
        tmp[tid] += t;
        __syncthreads();
    }
    if (i < NN) excl[i] = tmp[tid] - v;
    if (tid == 255) partials[blockIdx.x] = tmp[tid];
}

// single block: exclusive scan of NBLK partials in-place
__global__ void scan2_kernel(int* __restrict__ partials) {
    __shared__ int tmp[256];
    const int tid = threadIdx.x;
    const int v = (tid < NBLK) ? partials[tid] : 0;
    tmp[tid] = v;
    __syncthreads();
#pragma unroll
    for (int off = 1; off < 256; off <<= 1) {
        int t = (tid >= off) ? tmp[tid - off] : 0;
        __syncthreads();
        tmp[tid] += t;
        __syncthreads();
    }
    if (tid < NBLK) partials[tid] = tmp[tid] - v;  // exclusive
}

// rowstart = local excl + block offset; dinv = 1/sqrt(deg+1); cursor = 0
__global__ void scan3_kernel(const int* __restrict__ excl, const int* __restrict__ partials,
                             const int* __restrict__ deg, int* __restrict__ rowstart,
                             float* __restrict__ dinv, int* __restrict__ cursor) {
    const int i = blockIdx.x * 256 + threadIdx.x;
    if (i < NN) {
        rowstart[i] = excl[i] + partials[blockIdx.x];
        dinv[i] = 1.0f / sqrtf((float)deg[i] + 1.0f);
        cursor[i] = 0;
    }
}

__global__ void scatter_kernel(const int* __restrict__ src, const int* __restrict__ dst,
                               const int* __restrict__ rowstart, int* __restrict__ cursor,
                               int* __restrict__ csr_src) {
    int e = blockIdx.x * blockDim.x + threadIdx.x;
    if (e < NE) {
        const int d = dst[e];
        const int pos = rowstart[d] + atomicAdd(&cursor[d], 1);
        csr_src[pos] = src[e];
    }
}

// C[N,M] = A[N,K] @ W[K,M]; epilogue: optional *dinv[row] (SCALE) or +bias (BIAS).
template <int M, bool BIAS, bool SCALE>
__launch_bounds__(256)
__global__ void gemm_kernel(const float* __restrict__ A, const float* __restrict__ W,
                            const float* __restrict__ bias, const float* __restrict__ dinv,
                            float* __restrict__ C, int N, int K) {
    constexpr int KT = 16;
    constexpr int ROWS = 64;
    constexpr int TM = M / 16;
    __shared__ float sA[ROWS * KT];
    __shared__ float sW[KT * M];

    const int tid = threadIdx.x;
    const int tx = tid & 15;
    const int ty = tid >> 4;
    const int row0 = blockIdx.x * ROWS;

    float acc[4][TM];
#pragma unroll
    for (int i = 0; i < 4; ++i)
#pragma unroll
        for (int j = 0; j < TM; ++j) acc[i][j] = 0.0f;

    const int lr = tid >> 2;
    const int lc = (tid & 3) * 4;

    for (int k0 = 0; k0 < K; k0 += KT) {
        int arow = row0 + lr;
        if (arow >= N) arow = N - 1;
        const float4 av = *(const float4*)(A + (size_t)arow * K + k0 + lc);
        *(float4*)(sA + lr * KT + lc) = av;
#pragma unroll
        for (int i = tid; i < KT * M; i += 256) sW[i] = W[k0 * M + i];
        __syncthreads();

#pragma unroll
        for (int kk = 0; kk < KT; ++kk) {
            float a[4];
#pragma unroll
            for (int i = 0; i < 4; ++i) a[i] = sA[(ty * 4 + i) * KT + kk];
            float w[TM];
#pragma unroll
            for (int j = 0; j < TM; ++j) w[j] = sW[kk * M + tx * TM + j];
#pragma unroll
            for (int i = 0; i < 4; ++i)
#pragma unroll
                for (int j = 0; j < TM; ++j) acc[i][j] = fmaf(a[i], w[j], acc[i][j]);
        }
        __syncthreads();
    }

#pragma unroll
    for (int i = 0; i < 4; ++i) {
        const int row = row0 + ty * 4 + i;
        if (row < N) {
            const float s = SCALE ? dinv[row] : 1.0f;
#pragma unroll
            for (int j = 0; j < TM; ++j) {
                float v = acc[i][j];
                if (SCALE) v *= s;
                if (BIAS) v += bias[tx * TM + j];
                C[(size_t)row * M + tx * TM + j] = v;
            }
        }
    }
}

// gather-reduce: 24 threads per node, one float4 chunk each.
// out[i] = relu(dinv[i] * (sum_j hs[csr_src[j]] + hs[i]) + b)
constexpr int TPN = HIDD / 4;  // 24
__global__ void gather_kernel(const int* __restrict__ rowstart, const int* __restrict__ deg,
                              const int* __restrict__ csr_src, const float* __restrict__ dinv,
                              const float* __restrict__ hs, const float* __restrict__ b,
                              float* __restrict__ out) {
    const int t = blockIdx.x * blockDim.x + threadIdx.x;
    const int node = t / TPN;
    const int c = (t % TPN) * 4;
    if (node >= NN) return;

    const int r0 = rowstart[node];
    const int d = deg[node];
    const float* __restrict__ hsc = hs + c;

    // self-loop term
    float4 acc = *(const float4*)(hsc + (size_t)node * HIDD);
    float4 acc2 = make_float4(0.f, 0.f, 0.f, 0.f);

    int j = r0;
    const int jend = r0 + d;
    for (; j + 1 < jend; j += 2) {
        const int s0 = csr_src[j];
        const int s1 = csr_src[j + 1];
        const float4 v0 = *(const float4*)(hsc + (size_t)s0 * HIDD);
        const float4 v1 = *(const float4*)(hsc + (size_t)s1 * HIDD);
        acc.x += v0.x; acc.y += v0.y; acc.z += v0.z; acc.w += v0.w;
        acc2.x += v1.x; acc2.y += v1.y; acc2.z += v1.z; acc2.w += v1.w;
    }
    if (j < jend) {
        const int s0 = csr_src[j];
        const float4 v0 = *(const float4*)(hsc + (size_t)s0 * HIDD);
        acc.x += v0.x; acc.y += v0.y; acc.z += v0.z; acc.w += v0.w;
    }
    acc.x += acc2.x; acc.y += acc2.y; acc.z += acc2.z; acc.w += acc2.w;

    const float di = dinv[node];
    float4 o;
    o.x = fmaxf(fmaf(di, acc.x, b[c + 0]), 0.0f);
    o.y = fmaxf(fmaf(di, acc.y, b[c + 1]), 0.0f);
    o.z = fmaxf(fmaf(di, acc.z, b[c + 2]), 0.0f);
    o.w = fmaxf(fmaf(di, acc.w, b[c + 3]), 0.0f);
    *(float4*)(out + (size_t)node * HIDD + c) = o;
}

extern "C" void kernel_launch(void* const* d_in, const int* in_sizes, int n_in,
                              void* d_out, int out_size, void* d_ws, size_t ws_size,
                              hipStream_t stream) {
    const float* x   = (const float*)d_in[0];
    const int*   ei  = (const int*)d_in[1];
    const float* W0  = (const float*)d_in[2];
    const float* b0  = (const float*)d_in[3];
    const float* W1  = (const float*)d_in[4];
    const float* b1  = (const float*)d_in[5];
    const float* W2  = (const float*)d_in[6];
    const float* b2  = (const float*)d_in[7];
    const float* fcW = (const float*)d_in[8];
    const float* fcb = (const float*)d_in[9];
    float* out = (float*)d_out;

    const int* src = ei;
    const int* dst = ei + NE;

    // workspace layout (float-sized slots, 256-elem aligned)
    float* ws = (float*)d_ws;
    float* dinv     = ws;                       // [50000] f32
    int*   deg      = (int*)(ws + 50176);       // [50000] i32
    int*   excl     = (int*)(ws + 100352);      // [50000] i32 (scan scratch)
    int*   cursor   = (int*)(ws + 150528);      // [50000] i32
    int*   rowstart = (int*)(ws + 200704);      // [50000] i32
    int*   partials = (int*)(ws + 250880);      // [256]   i32
    int*   csr_src  = (int*)(ws + 251136);      // [800000] i32
    float* bufA     = ws + 1051392;             // [4.8M] f32
    float* bufB     = bufA + (size_t)NN * HIDD; // [4.8M] f32

    dim3 b256(256);
    const int gN = NBLK;                       // 196
    const int gE = (NE + 255) / 256;           // 3125
    const int gGem = (NN + 63) / 64;           // 782
    const int gGather = (NN * TPN + 191) / 192;// 6250

    // ---- CSR build + dinv ----
    zero_int_kernel<<<gN, b256, 0, stream>>>(deg, NN);
    hist_kernel<<<gE, b256, 0, stream>>>(dst, deg);
    scan1_kernel<<<gN, b256, 0, stream>>>(deg, excl, partials);
    scan2_kernel<<<1, b256, 0, stream>>>(partials);
    scan3_kernel<<<gN, b256, 0, stream>>>(excl, partials, deg, rowstart, dinv, cursor);
    scatter_kernel<<<gE, b256, 0, stream>>>(src, dst, rowstart, cursor, csr_src);

    // ---- layer 0: hs = (x@W0)*dinv ; gather(+self+bias+relu) ----
    gemm_kernel<HIDD, false, true><<<gGem, b256, 0, stream>>>(x, W0, nullptr, dinv, bufA, NN, KIN);
    gather_kernel<<<gGather, dim3(192), 0, stream>>>(rowstart, deg, csr_src, dinv, bufA, b0, bufB);

    // ---- layer 1 ----
    gemm_kernel<HIDD, false, true><<<gGem, b256, 0, stream>>>(bufB, W1, nullptr, dinv, bufA, NN, HIDD);
    gather_kernel<<<gGather, dim3(192), 0, stream>>>(rowstart, deg, csr_src, dinv, bufA, b1, bufB);

    // ---- layer 2 ----
    gemm_kernel<HIDD, false, true><<<gGem, b256, 0, stream>>>(bufB, W2, nullptr, dinv, bufA, NN, HIDD);
    gather_kernel<<<gGather, dim3(192), 0, stream>>>(rowstart, deg, csr_src, dinv, bufA, b2, bufB);

    // ---- fc ----
    gemm_kernel<ODIM, true, false><<<gGem, b256, 0, stream>>>(bufB, fcW, fcb, nullptr, out, NN, HIDD);
}

// Round 3
// 478.897 us; speedup vs baseline: 2.5209x; 1.1611x over previous
//
#include <hip/hip_runtime.h>

// GCN r3: split-bf16 MFMA GEMMs (a_hi*b_hi + a_lo*b_hi + a_hi*b_lo, fp32 acc)
// replace fp32 vector GEMMs. W preconverted to hi/lo bf16 packed in MFMA B-frag
// order. A-frags loaded direct from global (no LDS). CSR gather from r2 kept.

constexpr int NN   = 50000;
constexpr int NE   = 800000;
constexpr int KIN  = 512;
constexpr int HIDD = 96;
constexpr int ODIM = 64;
constexpr int NBLK = (NN + 255) / 256;   // 196 scan blocks

typedef short bf16x8 __attribute__((ext_vector_type(8)));
typedef float f32x4  __attribute__((ext_vector_type(4)));

__device__ inline short f2bf(float f) {               // RTN-even fp32 -> bf16 bits
    union { float f; unsigned u; } v; v.f = f;
    unsigned r = v.u + 0x7FFFu + ((v.u >> 16) & 1u);
    return (short)(r >> 16);
}
__device__ inline float bf2f(short h) {
    union { unsigned u; float f; } v; v.u = ((unsigned)(unsigned short)h) << 16;
    return v.f;
}

// ---------------- CSR build ----------------
__global__ void zero_int_kernel(int* __restrict__ p, int n) {
    int i = blockIdx.x * blockDim.x + threadIdx.x;
    if (i < n) p[i] = 0;
}

__global__ void hist_kernel(const int* __restrict__ dst, int* __restrict__ deg) {
    int e = blockIdx.x * blockDim.x + threadIdx.x;
    if (e < NE) atomicAdd(&deg[dst[e]], 1);
}

__global__ void scan1_kernel(const int* __restrict__ deg, int* __restrict__ excl,
                             int* __restrict__ partials) {
    __shared__ int tmp[256];
    const int tid = threadIdx.x;
    const int i = blockIdx.x * 256 + tid;
    const int v = (i < NN) ? deg[i] : 0;
    tmp[tid] = v;
    __syncthreads();
#pragma unroll
    for (int off = 1; off < 256; off <<= 1) {
        int t = (tid >= off) ? tmp[tid - off] : 0;
        __syncthreads();
        tmp[tid] += t;
        __syncthreads();
    }
    if (i < NN) excl[i] = tmp[tid] - v;
    if (tid == 255) partials[blockIdx.x] = tmp[tid];
}

__global__ void scan2_kernel(int* __restrict__ partials) {
    __shared__ int tmp[256];
    const int tid = threadIdx.x;
    const int v = (tid < NBLK) ? partials[tid] : 0;
    tmp[tid] = v;
    __syncthreads();
#pragma unroll
    for (int off = 1; off < 256; off <<= 1) {
        int t = (tid >= off) ? tmp[tid - off] : 0;
        __syncthreads();
        tmp[tid] += t;
        __syncthreads();
    }
    if (tid < NBLK) partials[tid] = tmp[tid] - v;
}

__global__ void scan3_kernel(const int* __restrict__ excl, const int* __restrict__ partials,
                             const int* __restrict__ deg, int* __restrict__ rowstart,
                             float* __restrict__ dinv, int* __restrict__ cursor) {
    const int i = blockIdx.x * 256 + threadIdx.x;
    if (i < NN) {
        rowstart[i] = excl[i] + partials[blockIdx.x];
        dinv[i] = 1.0f / sqrtf((float)deg[i] + 1.0f);
        cursor[i] = 0;
    }
}

__global__ void scatter_kernel(const int* __restrict__ src, const int* __restrict__ dst,
                               const int* __restrict__ rowstart, int* __restrict__ cursor,
                               int* __restrict__ csr_src) {
    int e = blockIdx.x * blockDim.x + threadIdx.x;
    if (e < NE) {
        const int d = dst[e];
        const int pos = rowstart[d] + atomicAdd(&cursor[d], 1);
        csr_src[pos] = src[e];
    }
}

// ---------------- W hi/lo pack (MFMA B-frag order) ----------------
// short index = ((kc*CT + ct)*64 + lane)*8 + j  maps to  W[kc*32 + (lane>>4)*8 + j][ct*16 + (lane&15)]
__global__ void pack_w(const float* __restrict__ W, short* __restrict__ hi,
                       short* __restrict__ lo, int K, int M) {
    const int CT = M >> 4;
    const int idx = blockIdx.x * 256 + threadIdx.x;
    if (idx >= K * M) return;
    const int j = idx & 7;
    const int lane = (idx >> 3) & 63;
    const int t = idx >> 9;            // kc*CT + ct
    const int ct = t % CT;
    const int kc = t / CT;
    const int k = kc * 32 + (lane >> 4) * 8 + j;
    const int n = ct * 16 + (lane & 15);
    const float w = W[k * M + n];
    const short h = f2bf(w);
    hi[idx] = h;
    lo[idx] = f2bf(w - bf2f(h));
}

// ---------------- split-bf16 MFMA GEMM ----------------
// C[N,M] = A[N,K] @ W[K,M]; epilogue: *dinv[row] (SCALE) or +bias (BIAS).
// Block = 4 waves; wave w owns rows blk*64 + w*16 .. +15, all M cols (CT tiles).
template <int M, bool BIAS, bool SCALE>
__launch_bounds__(256)
__global__ void mfma_gemm(const float* __restrict__ A, const bf16x8* __restrict__ Whi,
                          const bf16x8* __restrict__ Wlo, const float* __restrict__ bias,
                          const float* __restrict__ dinv, float* __restrict__ C,
                          int N, int K) {
    constexpr int CT = M / 16;
    const int lane = threadIdx.x & 63;
    const int wave = threadIdx.x >> 6;
    const int q = lane >> 4;           // quad 0..3
    const int m = lane & 15;
    const int row = blockIdx.x * 64 + wave * 16 + m;
    const int arow = (row < N) ? row : (N - 1);
    const int KC = K >> 5;

    f32x4 acc[CT];
#pragma unroll
    for (int c = 0; c < CT; ++c) acc[c] = f32x4{0.f, 0.f, 0.f, 0.f};

    const float* ap = A + (size_t)arow * K + q * 8;

    for (int kc = 0; kc < KC; ++kc) {
        const float4 a0 = *(const float4*)(ap);
        const float4 a1 = *(const float4*)(ap + 4);
        ap += 32;
        const float af[8] = {a0.x, a0.y, a0.z, a0.w, a1.x, a1.y, a1.z, a1.w};
        bf16x8 ahi, alo;
#pragma unroll
        for (int j = 0; j < 8; ++j) {
            const short h = f2bf(af[j]);
            ahi[j] = h;
            alo[j] = f2bf(af[j] - bf2f(h));
        }
#pragma unroll
        for (int c = 0; c < CT; ++c) {
            const bf16x8 wh = Whi[(kc * CT + c) * 64 + lane];
            const bf16x8 wl = Wlo[(kc * CT + c) * 64 + lane];
            acc[c] = __builtin_amdgcn_mfma_f32_16x16x32_bf16(ahi, wh, acc[c], 0, 0, 0);
            acc[c] = __builtin_amdgcn_mfma_f32_16x16x32_bf16(alo, wh, acc[c], 0, 0, 0);
            acc[c] = __builtin_amdgcn_mfma_f32_16x16x32_bf16(ahi, wl, acc[c], 0, 0, 0);
        }
    }

    // C/D layout (HW-measured): col = lane&15, row = (lane>>4)*4 + reg
    const int rbase = blockIdx.x * 64 + wave * 16 + q * 4;
#pragma unroll
    for (int r = 0; r < 4; ++r) {
        const int orow = rbase + r;
        if (orow < N) {
            const float s = SCALE ? dinv[orow] : 1.0f;
#pragma unroll
            for (int c = 0; c < CT; ++c) {
                float v = acc[c][r];
                if (SCALE) v *= s;
                if (BIAS) v += bias[c * 16 + m];
                C[(size_t)orow * M + c * 16 + m] = v;
            }
        }
    }
}

// ---------------- gather-reduce (unchanged from r2) ----------------
constexpr int TPN = HIDD / 4;  // 24
__global__ void gather_kernel(const int* __restrict__ rowstart, const int* __restrict__ deg,
                              const int* __restrict__ csr_src, const float* __restrict__ dinv,
                              const float* __restrict__ hs, const float* __restrict__ b,
                              float* __restrict__ out) {
    const int t = blockIdx.x * blockDim.x + threadIdx.x;
    const int node = t / TPN;
    const int c = (t % TPN) * 4;
    if (node >= NN) return;

    const int r0 = rowstart[node];
    const int d = deg[node];
    const float* __restrict__ hsc = hs + c;

    float4 acc = *(const float4*)(hsc + (size_t)node * HIDD);   // self-loop
    float4 acc2 = make_float4(0.f, 0.f, 0.f, 0.f);

    int j = r0;
    const int jend = r0 + d;
    for (; j + 1 < jend; j += 2) {
        const int s0 = csr_src[j];
        const int s1 = csr_src[j + 1];
        const float4 v0 = *(const float4*)(hsc + (size_t)s0 * HIDD);
        const float4 v1 = *(const float4*)(hsc + (size_t)s1 * HIDD);
        acc.x += v0.x; acc.y += v0.y; acc.z += v0.z; acc.w += v0.w;
        acc2.x += v1.x; acc2.y += v1.y; acc2.z += v1.z; acc2.w += v1.w;
    }
    if (j < jend) {
        const int s0 = csr_src[j];
        const float4 v0 = *(const float4*)(hsc + (size_t)s0 * HIDD);
        acc.x += v0.x; acc.y += v0.y; acc.z += v0.z; acc.w += v0.w;
    }
    acc.x += acc2.x; acc.y += acc2.y; acc.z += acc2.z; acc.w += acc2.w;

    const float di = dinv[node];
    float4 o;
    o.x = fmaxf(fmaf(di, acc.x, b[c + 0]), 0.0f);
    o.y = fmaxf(fmaf(di, acc.y, b[c + 1]), 0.0f);
    o.z = fmaxf(fmaf(di, acc.z, b[c + 2]), 0.0f);
    o.w = fmaxf(fmaf(di, acc.w, b[c + 3]), 0.0f);
    *(float4*)(out + (size_t)node * HIDD + c) = o;
}

extern "C" void kernel_launch(void* const* d_in, const int* in_sizes, int n_in,
                              void* d_out, int out_size, void* d_ws, size_t ws_size,
                              hipStream_t stream) {
    const float* x   = (const float*)d_in[0];
    const int*   ei  = (const int*)d_in[1];
    const float* W0  = (const float*)d_in[2];
    const float* b0  = (const float*)d_in[3];
    const float* W1  = (const float*)d_in[4];
    const float* b1  = (const float*)d_in[5];
    const float* W2  = (const float*)d_in[6];
    const float* b2  = (const float*)d_in[7];
    const float* fcW = (const float*)d_in[8];
    const float* fcb = (const float*)d_in[9];
    float* out = (float*)d_out;

    const int* src = ei;
    const int* dst = ei + NE;

    // workspace layout (float-sized slots, 16B-aligned offsets)
    float* ws = (float*)d_ws;
    float* dinv     = ws;                       // [50000] f32
    int*   deg      = (int*)(ws + 50176);       // [50000]
    int*   excl     = (int*)(ws + 100352);      // [50000]
    int*   cursor   = (int*)(ws + 150528);      // [50000]
    int*   rowstart = (int*)(ws + 200704);      // [50000]
    int*   partials = (int*)(ws + 250880);      // [256]
    int*   csr_src  = (int*)(ws + 251136);      // [800000]
    short* w0hi = (short*)(ws + 1051392);       // [49152] sh
    short* w0lo = (short*)(ws + 1075968);
    short* w1hi = (short*)(ws + 1100544);       // [9216] sh
    short* w1lo = (short*)(ws + 1105152);
    short* w2hi = (short*)(ws + 1109760);
    short* w2lo = (short*)(ws + 1114368);
    short* fchi = (short*)(ws + 1118976);       // [6144] sh
    short* fclo = (short*)(ws + 1122048);
    float* bufA = ws + 1125120;                 // [4.8M] f32
    float* bufB = bufA + (size_t)NN * HIDD;     // [4.8M] f32

    dim3 b256(256);
    const int gN = NBLK;                        // 196
    const int gE = (NE + 255) / 256;            // 3125
    const int gGem = (NN + 63) / 64;            // 782
    const int gGather = (NN * TPN + 191) / 192; // 6250

    // ---- CSR build + dinv ----
    zero_int_kernel<<<gN, b256, 0, stream>>>(deg, NN);
    hist_kernel<<<gE, b256, 0, stream>>>(dst, deg);
    scan1_kernel<<<gN, b256, 0, stream>>>(deg, excl, partials);
    scan2_kernel<<<1, b256, 0, stream>>>(partials);
    scan3_kernel<<<gN, b256, 0, stream>>>(excl, partials, deg, rowstart, dinv, cursor);
    scatter_kernel<<<gE, b256, 0, stream>>>(src, dst, rowstart, cursor, csr_src);

    // ---- pack weights to hi/lo bf16 fragments ----
    pack_w<<<(KIN * HIDD + 255) / 256, b256, 0, stream>>>(W0, w0hi, w0lo, KIN, HIDD);
    pack_w<<<(HIDD * HIDD + 255) / 256, b256, 0, stream>>>(W1, w1hi, w1lo, HIDD, HIDD);
    pack_w<<<(HIDD * HIDD + 255) / 256, b256, 0, stream>>>(W2, w2hi, w2lo, HIDD, HIDD);
    pack_w<<<(HIDD * ODIM + 255) / 256, b256, 0, stream>>>(fcW, fchi, fclo, HIDD, ODIM);

    // ---- layer 0: hs = (x@W0)*dinv ; gather(+self+bias+relu) ----
    mfma_gemm<HIDD, false, true><<<gGem, b256, 0, stream>>>(
        x, (const bf16x8*)w0hi, (const bf16x8*)w0lo, nullptr, dinv, bufA, NN, KIN);
    gather_kernel<<<gGather, dim3(192), 0, stream>>>(rowstart, deg, csr_src, dinv, bufA, b0, bufB);

    // ---- layer 1 ----
    mfma_gemm<HIDD, false, true><<<gGem, b256, 0, stream>>>(
        bufB, (const bf16x8*)w1hi, (const bf16x8*)w1lo, nullptr, dinv, bufA, NN, HIDD);
    gather_kernel<<<gGather, dim3(192), 0, stream>>>(rowstart, deg, csr_src, dinv, bufA, b1, bufB);

    // ---- layer 2 ----
    mfma_gemm<HIDD, false, true><<<gGem, b256, 0, stream>>>(
        bufB, (const bf16x8*)w2hi, (const bf16x8*)w2lo, nullptr, dinv, bufA, NN, HIDD);
    gather_kernel<<<gGather, dim3(192), 0, stream>>>(rowstart, deg, csr_src, dinv, bufA, b2, bufB);

    // ---- fc: out = h @ fcW + fcb ----
    mfma_gemm<ODIM, true, false><<<gGem, b256, 0, stream>>>(
        bufB, (const bf16x8*)fchi, (const bf16x8*)fclo, fcb, nullptr, out, NN, HIDD);
}

// Round 4
// 460.080 us; speedup vs baseline: 2.6240x; 1.0409x over previous
//
#include <hip/hip_runtime.h>

// GCN r4: (1) software-pipelined layer-0 MFMA GEMM (A prefetch, W loads covered
// by conversion VALU); (2) gather with 4-deep load prefetch; (3) gather emits
// hi/lo bf16 A-planes so K=96 GEMMs + fc do zero conversion work.

constexpr int NN   = 50000;
constexpr int NE   = 800000;
constexpr int KIN  = 512;
constexpr int HIDD = 96;
constexpr int ODIM = 64;
constexpr int NBLK = (NN + 255) / 256;   // 196 scan blocks

typedef short bf16x8 __attribute__((ext_vector_type(8)));
typedef float f32x4  __attribute__((ext_vector_type(4)));

__device__ inline short f2bf(float f) {               // RTN-even fp32 -> bf16 bits
    union { float f; unsigned u; } v; v.f = f;
    unsigned r = v.u + 0x7FFFu + ((v.u >> 16) & 1u);
    return (short)(r >> 16);
}
__device__ inline short f2bf_trunc(float f) {         // truncate (for lo residual)
    union { float f; unsigned u; } v; v.f = f;
    return (short)(v.u >> 16);
}
__device__ inline float bf2f(short h) {
    union { unsigned u; float f; } v; v.u = ((unsigned)(unsigned short)h) << 16;
    return v.f;
}

// ---------------- CSR build ----------------
__global__ void zero_int_kernel(int* __restrict__ p, int n) {
    int i = blockIdx.x * blockDim.x + threadIdx.x;
    if (i < n) p[i] = 0;
}

__global__ void hist_kernel(const int* __restrict__ dst, int* __restrict__ deg) {
    int e = blockIdx.x * blockDim.x + threadIdx.x;
    if (e < NE) atomicAdd(&deg[dst[e]], 1);
}

__global__ void scan1_kernel(const int* __restrict__ deg, int* __restrict__ excl,
                             int* __restrict__ partials) {
    __shared__ int tmp[256];
    const int tid = threadIdx.x;
    const int i = blockIdx.x * 256 + tid;
    const int v = (i < NN) ? deg[i] : 0;
    tmp[tid] = v;
    __syncthreads();
#pragma unroll
    for (int off = 1; off < 256; off <<= 1) {
        int t = (tid >= off) ? tmp[tid - off] : 0;
        __syncthreads();
        tmp[tid] += t;
        __syncthreads();
    }
    if (i < NN) excl[i] = tmp[tid] - v;
    if (tid == 255) partials[blockIdx.x] = tmp[tid];
}

__global__ void scan2_kernel(int* __restrict__ partials) {
    __shared__ int tmp[256];
    const int tid = threadIdx.x;
    const int v = (tid < NBLK) ? partials[tid] : 0;
    tmp[tid] = v;
    __syncthreads();
#pragma unroll
    for (int off = 1; off < 256; off <<= 1) {
        int t = (tid >= off) ? tmp[tid - off] : 0;
        __syncthreads();
        tmp[tid] += t;
        __syncthreads();
    }
    if (tid < NBLK) partials[tid] = tmp[tid] - v;
}

__global__ void scan3_kernel(const int* __restrict__ excl, const int* __restrict__ partials,
                             const int* __restrict__ deg, int* __restrict__ rowstart,
                             float* __restrict__ dinv, int* __restrict__ cursor) {
    const int i = blockIdx.x * 256 + threadIdx.x;
    if (i < NN) {
        rowstart[i] = excl[i] + partials[blockIdx.x];
        dinv[i] = 1.0f / sqrtf((float)deg[i] + 1.0f);
        cursor[i] = 0;
    }
}

__global__ void scatter_kernel(const int* __restrict__ src, const int* __restrict__ dst,
                               const int* __restrict__ rowstart, int* __restrict__ cursor,
                               int* __restrict__ csr_src) {
    int e = blockIdx.x * blockDim.x + threadIdx.x;
    if (e < NE) {
        const int d = dst[e];
        const int pos = rowstart[d] + atomicAdd(&cursor[d], 1);
        csr_src[pos] = src[e];
    }
}

// ---------------- W hi/lo pack (MFMA B-frag order) ----------------
// short index = ((kc*CT + ct)*64 + lane)*8 + j  <-  W[kc*32 + (lane>>4)*8 + j][ct*16 + (lane&15)]
__global__ void pack_w(const float* __restrict__ W, short* __restrict__ hi,
                       short* __restrict__ lo, int K, int M) {
    const int CT = M >> 4;
    const int idx = blockIdx.x * 256 + threadIdx.x;
    if (idx >= K * M) return;
    const int j = idx & 7;
    const int lane = (idx >> 3) & 63;
    const int t = idx >> 9;            // kc*CT + ct
    const int ct = t % CT;
    const int kc = t / CT;
    const int k = kc * 32 + (lane >> 4) * 8 + j;
    const int n = ct * 16 + (lane & 15);
    const float w = W[k * M + n];
    const short h = f2bf(w);
    hi[idx] = h;
    lo[idx] = f2bf_trunc(w - bf2f(h));
}

// ---------------- layer-0 GEMM: fp32 A, split-bf16, software-pipelined ----------------
// C[N,96] = A[N,K] @ W[K,96], epilogue *dinv[row].
template <int K>
__launch_bounds__(256, 3)
__global__ void mfma_gemm_f(const float* __restrict__ A, const bf16x8* __restrict__ Whi,
                            const bf16x8* __restrict__ Wlo, const float* __restrict__ dinv,
                            float* __restrict__ C, int N) {
    constexpr int CT = 6;              // 96/16
    constexpr int KC = K / 32;
    const int lane = threadIdx.x & 63;
    const int wave = threadIdx.x >> 6;
    const int q = lane >> 4;
    const int m = lane & 15;
    const int row = blockIdx.x * 64 + wave * 16 + m;
    const int arow = (row < N) ? row : (N - 1);

    f32x4 acc[CT];
#pragma unroll
    for (int c = 0; c < CT; ++c) acc[c] = f32x4{0.f, 0.f, 0.f, 0.f};

    const float* ap = A + (size_t)arow * K + q * 8;
    // prologue: A(kc=0) in flight
    float4 a0 = *(const float4*)(ap);
    float4 a1 = *(const float4*)(ap + 4);

#pragma unroll
    for (int kc = 0; kc < KC; ++kc) {
        // issue W loads for this kc (L2-hot; latency covered by conversion below)
        bf16x8 wh[CT], wl[CT];
#pragma unroll
        for (int c = 0; c < CT; ++c) wh[c] = Whi[(kc * CT + c) * 64 + lane];
#pragma unroll
        for (int c = 0; c < CT; ++c) wl[c] = Wlo[(kc * CT + c) * 64 + lane];

        // convert current A (waits only on a0/a1)
        const float af[8] = {a0.x, a0.y, a0.z, a0.w, a1.x, a1.y, a1.z, a1.w};
        bf16x8 ahi, alo;
#pragma unroll
        for (int j = 0; j < 8; ++j) {
            const short h = f2bf(af[j]);
            ahi[j] = h;
            alo[j] = f2bf_trunc(af[j] - bf2f(h));
        }

        // prefetch next A (HBM-latency; hidden behind MFMAs below)
        if (kc + 1 < KC) {
            ap += 32;
            a0 = *(const float4*)(ap);
            a1 = *(const float4*)(ap + 4);
        }

#pragma unroll
        for (int c = 0; c < CT; ++c) {
            acc[c] = __builtin_amdgcn_mfma_f32_16x16x32_bf16(ahi, wh[c], acc[c], 0, 0, 0);
            acc[c] = __builtin_amdgcn_mfma_f32_16x16x32_bf16(alo, wh[c], acc[c], 0, 0, 0);
            acc[c] = __builtin_amdgcn_mfma_f32_16x16x32_bf16(ahi, wl[c], acc[c], 0, 0, 0);
        }
    }

    // C/D layout: col = lane&15, row = (lane>>4)*4 + reg
    const int rbase = blockIdx.x * 64 + wave * 16 + q * 4;
#pragma unroll
    for (int r = 0; r < 4; ++r) {
        const int orow = rbase + r;
        if (orow < N) {
            const float s = dinv[orow];
#pragma unroll
            for (int c = 0; c < CT; ++c)
                C[(size_t)orow * 96 + c * 16 + m] = acc[c][r] * s;
        }
    }
}

// ---------------- K=96 GEMMs + fc: bf16 hi/lo A-planes, no conversion ----------------
template <int M, int K, bool BIAS, bool SCALE>
__launch_bounds__(256)
__global__ void mfma_gemm_b(const short* __restrict__ Ahi, const short* __restrict__ Alo,
                            const bf16x8* __restrict__ Whi, const bf16x8* __restrict__ Wlo,
                            const float* __restrict__ bias, const float* __restrict__ dinv,
                            float* __restrict__ C, int N) {
    constexpr int CT = M / 16;
    constexpr int KC = K / 32;
    const int lane = threadIdx.x & 63;
    const int wave = threadIdx.x >> 6;
    const int q = lane >> 4;
    const int m = lane & 15;
    const int row = blockIdx.x * 64 + wave * 16 + m;
    const int arow = (row < N) ? row : (N - 1);

    f32x4 acc[CT];
#pragma unroll
    for (int c = 0; c < CT; ++c) acc[c] = f32x4{0.f, 0.f, 0.f, 0.f};

    const short* ah = Ahi + (size_t)arow * K + q * 8;
    const short* al = Alo + (size_t)arow * K + q * 8;

#pragma unroll
    for (int kc = 0; kc < KC; ++kc) {
        const bf16x8 ahi = *(const bf16x8*)(ah + kc * 32);
        const bf16x8 alo = *(const bf16x8*)(al + kc * 32);
#pragma unroll
        for (int c = 0; c < CT; ++c) {
            const bf16x8 wh = Whi[(kc * CT + c) * 64 + lane];
            const bf16x8 wl = Wlo[(kc * CT + c) * 64 + lane];
            acc[c] = __builtin_amdgcn_mfma_f32_16x16x32_bf16(ahi, wh, acc[c], 0, 0, 0);
            acc[c] = __builtin_amdgcn_mfma_f32_16x16x32_bf16(alo, wh, acc[c], 0, 0, 0);
            acc[c] = __builtin_amdgcn_mfma_f32_16x16x32_bf16(ahi, wl, acc[c], 0, 0, 0);
        }
    }

    const int rbase = blockIdx.x * 64 + wave * 16 + q * 4;
#pragma unroll
    for (int r = 0; r < 4; ++r) {
        const int orow = rbase + r;
        if (orow < N) {
            const float s = SCALE ? dinv[orow] : 1.0f;
#pragma unroll
            for (int c = 0; c < CT; ++c) {
                float v = acc[c][r];
                if (SCALE) v *= s;
                if (BIAS) v += bias[c * 16 + m];
                C[(size_t)orow * M + c * 16 + m] = v;
            }
        }
    }
}

// ---------------- gather-reduce: 4-deep prefetch; emits hi/lo bf16 planes ----------------
constexpr int TPN = HIDD / 4;  // 24 threads/node, one float4 chunk each
__launch_bounds__(192)
__global__ void gather_kernel(const int* __restrict__ rowstart, const int* __restrict__ deg,
                              const int* __restrict__ csr_src, const float* __restrict__ dinv,
                              const float* __restrict__ hs, const float* __restrict__ b,
                              short* __restrict__ outhi, short* __restrict__ outlo) {
    const int t = blockIdx.x * blockDim.x + threadIdx.x;
    const int node = t / TPN;
    const int c = (t % TPN) * 4;
    if (node >= NN) return;

    const int r0 = rowstart[node];
    const int d = deg[node];
    const float* __restrict__ hsc = hs + c;

    float4 acc0 = *(const float4*)(hsc + (size_t)node * HIDD);   // self-loop
    float4 acc1 = make_float4(0.f, 0.f, 0.f, 0.f);
    float4 acc2 = make_float4(0.f, 0.f, 0.f, 0.f);
    float4 acc3 = make_float4(0.f, 0.f, 0.f, 0.f);

    int j = r0;
    const int jend = r0 + d;
    for (; j + 4 <= jend; j += 4) {
        const int s0 = csr_src[j];
        const int s1 = csr_src[j + 1];
        const int s2 = csr_src[j + 2];
        const int s3 = csr_src[j + 3];
        const float4 v0 = *(const float4*)(hsc + (size_t)s0 * HIDD);
        const float4 v1 = *(const float4*)(hsc + (size_t)s1 * HIDD);
        const float4 v2 = *(const float4*)(hsc + (size_t)s2 * HIDD);
        const float4 v3 = *(const float4*)(hsc + (size_t)s3 * HIDD);
        acc0.x += v0.x; acc0.y += v0.y; acc0.z += v0.z; acc0.w += v0.w;
        acc1.x += v1.x; acc1.y += v1.y; acc1.z += v1.z; acc1.w += v1.w;
        acc2.x += v2.x; acc2.y += v2.y; acc2.z += v2.z; acc2.w += v2.w;
        acc3.x += v3.x; acc3.y += v3.y; acc3.z += v3.z; acc3.w += v3.w;
    }
    for (; j < jend; ++j) {
        const int s0 = csr_src[j];
        const float4 v0 = *(const float4*)(hsc + (size_t)s0 * HIDD);
        acc0.x += v0.x; acc0.y += v0.y; acc0.z += v0.z; acc0.w += v0.w;
    }
    acc0.x += acc1.x; acc0.y += acc1.y; acc0.z += acc1.z; acc0.w += acc1.w;
    acc2.x += acc3.x; acc2.y += acc3.y; acc2.z += acc3.z; acc2.w += acc3.w;
    acc0.x += acc2.x; acc0.y += acc2.y; acc0.z += acc2.z; acc0.w += acc2.w;

    const float di = dinv[node];
    float o[4];
    o[0] = fmaxf(fmaf(di, acc0.x, b[c + 0]), 0.0f);
    o[1] = fmaxf(fmaf(di, acc0.y, b[c + 1]), 0.0f);
    o[2] = fmaxf(fmaf(di, acc0.z, b[c + 2]), 0.0f);
    o[3] = fmaxf(fmaf(di, acc0.w, b[c + 3]), 0.0f);

    short4 hi, lo;
    hi.x = f2bf(o[0]); lo.x = f2bf_trunc(o[0] - bf2f(hi.x));
    hi.y = f2bf(o[1]); lo.y = f2bf_trunc(o[1] - bf2f(hi.y));
    hi.z = f2bf(o[2]); lo.z = f2bf_trunc(o[2] - bf2f(hi.z));
    hi.w = f2bf(o[3]); lo.w = f2bf_trunc(o[3] - bf2f(hi.w));
    *(short4*)(outhi + (size_t)node * HIDD + c) = hi;
    *(short4*)(outlo + (size_t)node * HIDD + c) = lo;
}

extern "C" void kernel_launch(void* const* d_in, const int* in_sizes, int n_in,
                              void* d_out, int out_size, void* d_ws, size_t ws_size,
                              hipStream_t stream) {
    const float* x   = (const float*)d_in[0];
    const int*   ei  = (const int*)d_in[1];
    const float* W0  = (const float*)d_in[2];
    const float* b0  = (const float*)d_in[3];
    const float* W1  = (const float*)d_in[4];
    const float* b1  = (const float*)d_in[5];
    const float* W2  = (const float*)d_in[6];
    const float* b2  = (const float*)d_in[7];
    const float* fcW = (const float*)d_in[8];
    const float* fcb = (const float*)d_in[9];
    float* out = (float*)d_out;

    const int* src = ei;
    const int* dst = ei + NE;

    // workspace layout (float-sized slots, 16B-aligned offsets)
    float* ws = (float*)d_ws;
    float* dinv     = ws;                       // [50000] f32
    int*   deg      = (int*)(ws + 50176);
    int*   excl     = (int*)(ws + 100352);
    int*   cursor   = (int*)(ws + 150528);
    int*   rowstart = (int*)(ws + 200704);
    int*   partials = (int*)(ws + 250880);      // [256]
    int*   csr_src  = (int*)(ws + 251136);      // [800000]
    short* w0hi = (short*)(ws + 1051392);       // [49152] shorts
    short* w0lo = (short*)(ws + 1075968);
    short* w1hi = (short*)(ws + 1100544);       // [9216] shorts
    short* w1lo = (short*)(ws + 1105152);
    short* w2hi = (short*)(ws + 1109760);
    short* w2lo = (short*)(ws + 1114368);
    short* fchi = (short*)(ws + 1118976);       // [6144] shorts
    short* fclo = (short*)(ws + 1122048);
    float* bufA = ws + 1125120;                 // [4.8M] f32  (hs, fp32)
    short* Hhi  = (short*)(bufA + (size_t)NN * HIDD);   // [4.8M] shorts
    short* Hlo  = (short*)(bufA + (size_t)NN * HIDD + 2400000);

    dim3 b256(256);
    const int gN = NBLK;                        // 196
    const int gE = (NE + 255) / 256;            // 3125
    const int gGem = (NN + 63) / 64;            // 782
    const int gGather = (NN * TPN + 191) / 192; // 6250

    // ---- CSR build + dinv ----
    zero_int_kernel<<<gN, b256, 0, stream>>>(deg, NN);
    hist_kernel<<<gE, b256, 0, stream>>>(dst, deg);
    scan1_kernel<<<gN, b256, 0, stream>>>(deg, excl, partials);
    scan2_kernel<<<1, b256, 0, stream>>>(partials);
    scan3_kernel<<<gN, b256, 0, stream>>>(excl, partials, deg, rowstart, dinv, cursor);
    scatter_kernel<<<gE, b256, 0, stream>>>(src, dst, rowstart, cursor, csr_src);

    // ---- pack weights ----
    pack_w<<<(KIN * HIDD + 255) / 256, b256, 0, stream>>>(W0, w0hi, w0lo, KIN, HIDD);
    pack_w<<<(HIDD * HIDD + 255) / 256, b256, 0, stream>>>(W1, w1hi, w1lo, HIDD, HIDD);
    pack_w<<<(HIDD * HIDD + 255) / 256, b256, 0, stream>>>(W2, w2hi, w2lo, HIDD, HIDD);
    pack_w<<<(HIDD * ODIM + 255) / 256, b256, 0, stream>>>(fcW, fchi, fclo, HIDD, ODIM);

    // ---- layer 0 ----
    mfma_gemm_f<KIN><<<gGem, b256, 0, stream>>>(
        x, (const bf16x8*)w0hi, (const bf16x8*)w0lo, dinv, bufA, NN);
    gather_kernel<<<gGather, dim3(192), 0, stream>>>(rowstart, deg, csr_src, dinv, bufA, b0, Hhi, Hlo);

    // ---- layer 1 ----
    mfma_gemm_b<HIDD, HIDD, false, true><<<gGem, b256, 0, stream>>>(
        Hhi, Hlo, (const bf16x8*)w1hi, (const bf16x8*)w1lo, nullptr, dinv, bufA, NN);
    gather_kernel<<<gGather, dim3(192), 0, stream>>>(rowstart, deg, csr_src, dinv, bufA, b1, Hhi, Hlo);

    // ---- layer 2 ----
    mfma_gemm_b<HIDD, HIDD, false, true><<<gGem, b256, 0, stream>>>(
        Hhi, Hlo, (const bf16x8*)w2hi, (const bf16x8*)w2lo, nullptr, dinv, bufA, NN);
    gather_kernel<<<gGather, dim3(192), 0, stream>>>(rowstart, deg, csr_src, dinv, bufA, b2, Hhi, Hlo);

    // ---- fc ----
    mfma_gemm_b<ODIM, HIDD, true, false><<<gGem, b256, 0, stream>>>(
        Hhi, Hlo, (const bf16x8*)fchi, (const bf16x8*)fclo, fcb, nullptr, out, NN);
}

// Round 5
// 414.721 us; speedup vs baseline: 2.9110x; 1.1094x over previous
//
#include <hip/hip_runtime.h>

// GCN r5: (1) hs carried as fp16 (halves gather's random-read working set),
// (2) split-K x2 layer-0 GEMM (8-wave blocks, LDS combine) for 2x wave count,
// (3) split-N x2 K=96 GEMMs, (4) fused pack + fused scan2->scan3 (fewer launches).

constexpr int NN   = 50000;
constexpr int NE   = 800000;
constexpr int KIN  = 512;
constexpr int HIDD = 96;
constexpr int ODIM = 64;
constexpr int NBLK = (NN + 255) / 256;   // 196 scan blocks

typedef short bf16x8 __attribute__((ext_vector_type(8)));
typedef float f32x4  __attribute__((ext_vector_type(4)));
typedef _Float16 h4  __attribute__((ext_vector_type(4)));

__device__ inline short f2bf(float f) {               // RTN-even fp32 -> bf16 bits
    union { float f; unsigned u; } v; v.f = f;
    unsigned r = v.u + 0x7FFFu + ((v.u >> 16) & 1u);
    return (short)(r >> 16);
}
__device__ inline short f2bf_trunc(float f) {         // truncate (for lo residual)
    union { float f; unsigned u; } v; v.f = f;
    return (short)(v.u >> 16);
}
__device__ inline float bf2f(short h) {
    union { unsigned u; float f; } v; v.u = ((unsigned)(unsigned short)h) << 16;
    return v.f;
}

// ---------------- CSR build ----------------
__global__ void zero_int_kernel(int* __restrict__ p, int n) {
    int i = blockIdx.x * blockDim.x + threadIdx.x;
    if (i < n) p[i] = 0;
}

__global__ void hist_kernel(const int* __restrict__ dst, int* __restrict__ deg) {
    int e = blockIdx.x * blockDim.x + threadIdx.x;
    if (e < NE) atomicAdd(&deg[dst[e]], 1);
}

__global__ void scan1_kernel(const int* __restrict__ deg, int* __restrict__ excl,
                             int* __restrict__ partials) {
    __shared__ int tmp[256];
    const int tid = threadIdx.x;
    const int i = blockIdx.x * 256 + tid;
    const int v = (i < NN) ? deg[i] : 0;
    tmp[tid] = v;
    __syncthreads();
#pragma unroll
    for (int off = 1; off < 256; off <<= 1) {
        int t = (tid >= off) ? tmp[tid - off] : 0;
        __syncthreads();
        tmp[tid] += t;
        __syncthreads();
    }
    if (i < NN) excl[i] = tmp[tid] - v;
    if (tid == 255) partials[blockIdx.x] = tmp[tid];
}

// fused: block offset = sum(partials[0..bid)) via tree-reduce; then rowstart/dinv/cursor
__global__ void scan3_kernel(const int* __restrict__ excl, const int* __restrict__ partials,
                             const int* __restrict__ deg, int* __restrict__ rowstart,
                             float* __restrict__ dinv, int* __restrict__ cursor) {
    __shared__ int tmp[256];
    const int tid = threadIdx.x;
    tmp[tid] = (tid < (int)blockIdx.x) ? partials[tid] : 0;   // NBLK=196 <= 256
    __syncthreads();
#pragma unroll
    for (int off = 128; off > 0; off >>= 1) {
        if (tid < off) tmp[tid] += tmp[tid + off];
        __syncthreads();
    }
    const int boff = tmp[0];
    const int i = blockIdx.x * 256 + tid;
    if (i < NN) {
        rowstart[i] = excl[i] + boff;
        dinv[i] = 1.0f / sqrtf((float)deg[i] + 1.0f);
        cursor[i] = 0;
    }
}

__global__ void scatter_kernel(const int* __restrict__ src, const int* __restrict__ dst,
                               const int* __restrict__ rowstart, int* __restrict__ cursor,
                               int* __restrict__ csr_src) {
    int e = blockIdx.x * blockDim.x + threadIdx.x;
    if (e < NE) {
        const int d = dst[e];
        const int pos = rowstart[d] + atomicAdd(&cursor[d], 1);
        csr_src[pos] = src[e];
    }
}

// ---------------- fused W hi/lo pack (MFMA B-frag order) ----------------
// short index li = ((kc*CT + ct)*64 + lane)*8 + j <- W[kc*32 + (lane>>4)*8 + j][ct*16 + (lane&15)]
__global__ void pack_all(const float* __restrict__ W0, const float* __restrict__ W1,
                         const float* __restrict__ W2, const float* __restrict__ FC,
                         short* __restrict__ w0hi, short* __restrict__ w0lo,
                         short* __restrict__ w1hi, short* __restrict__ w1lo,
                         short* __restrict__ w2hi, short* __restrict__ w2lo,
                         short* __restrict__ fchi, short* __restrict__ fclo) {
    const int idx = blockIdx.x * 256 + threadIdx.x;
    const float* W; short *hi, *lo; int M, li;
    if      (idx < 49152) { W = W0; hi = w0hi; lo = w0lo; M = 96; li = idx; }
    else if (idx < 58368) { W = W1; hi = w1hi; lo = w1lo; M = 96; li = idx - 49152; }
    else if (idx < 67584) { W = W2; hi = w2hi; lo = w2lo; M = 96; li = idx - 58368; }
    else if (idx < 73728) { W = FC; hi = fchi; lo = fclo; M = 64; li = idx - 67584; }
    else return;
    const int CT = M >> 4;
    const int j = li & 7;
    const int lane = (li >> 3) & 63;
    const int t = li >> 9;             // kc*CT + ct
    const int ct = t % CT;
    const int kc = t / CT;
    const int k = kc * 32 + (lane >> 4) * 8 + j;
    const int n = ct * 16 + (lane & 15);
    const float w = W[k * M + n];
    const short h = f2bf(w);
    hi[li] = h;
    lo[li] = f2bf_trunc(w - bf2f(h));
}

// ---------------- layer-0 GEMM: fp32 A, split-bf16, split-K x2 ----------------
// C_h16[N,96] = (A[N,K] @ W[K,96]) * dinv[row], fp16 output.
// 512 threads = 8 waves: wave&3 -> row group (16 rows), wave>>2 -> K half.
template <int K>
__launch_bounds__(512, 4)
__global__ void mfma_gemm_f(const float* __restrict__ A, const bf16x8* __restrict__ Whi,
                            const bf16x8* __restrict__ Wlo, const float* __restrict__ dinv,
                            _Float16* __restrict__ C, int N) {
    constexpr int CT = 6;
    constexpr int KC = K / 32;     // 16
    constexpr int KCH = KC / 2;    // 8
    __shared__ f32x4 sAcc[4 * 64 * CT];   // 24 KB

    const int lane = threadIdx.x & 63;
    const int wave = threadIdx.x >> 6;
    const int rw = wave & 3;
    const int kh = wave >> 2;
    const int q = lane >> 4;
    const int m = lane & 15;
    const int row = blockIdx.x * 64 + rw * 16 + m;
    const int arow = (row < N) ? row : (N - 1);

    f32x4 acc[CT];
#pragma unroll
    for (int c = 0; c < CT; ++c) acc[c] = f32x4{0.f, 0.f, 0.f, 0.f};

    const float* ap = A + (size_t)arow * K + kh * (K / 2) + q * 8;
    float4 a0 = *(const float4*)(ap);
    float4 a1 = *(const float4*)(ap + 4);

#pragma unroll
    for (int kc = 0; kc < KCH; ++kc) {
        const int kg = kh * KCH + kc;
        // convert current A
        const float af[8] = {a0.x, a0.y, a0.z, a0.w, a1.x, a1.y, a1.z, a1.w};
        bf16x8 ahi, alo;
#pragma unroll
        for (int j = 0; j < 8; ++j) {
            const short h = f2bf(af[j]);
            ahi[j] = h;
            alo[j] = f2bf_trunc(af[j] - bf2f(h));
        }
        // prefetch next A (hidden behind MFMAs)
        if (kc + 1 < KCH) {
            ap += 32;
            a0 = *(const float4*)(ap);
            a1 = *(const float4*)(ap + 4);
        }
        // W frags in two batches of 3 to bound VGPR pressure
#pragma unroll
        for (int half = 0; half < 2; ++half) {
            bf16x8 wh[3], wl[3];
#pragma unroll
            for (int c = 0; c < 3; ++c) wh[c] = Whi[(kg * CT + half * 3 + c) * 64 + lane];
#pragma unroll
            for (int c = 0; c < 3; ++c) wl[c] = Wlo[(kg * CT + half * 3 + c) * 64 + lane];
#pragma unroll
            for (int c = 0; c < 3; ++c) {
                const int cc = half * 3 + c;
                acc[cc] = __builtin_amdgcn_mfma_f32_16x16x32_bf16(ahi, wh[c], acc[cc], 0, 0, 0);
                acc[cc] = __builtin_amdgcn_mfma_f32_16x16x32_bf16(alo, wh[c], acc[cc], 0, 0, 0);
                acc[cc] = __builtin_amdgcn_mfma_f32_16x16x32_bf16(ahi, wl[c], acc[cc], 0, 0, 0);
            }
        }
    }

    // combine K halves through LDS
    if (kh == 1) {
#pragma unroll
        for (int c = 0; c < CT; ++c) sAcc[(rw * 64 + lane) * CT + c] = acc[c];
    }
    __syncthreads();
    if (kh == 0) {
#pragma unroll
        for (int c = 0; c < CT; ++c) {
            const f32x4 o = sAcc[(rw * 64 + lane) * CT + c];
            acc[c][0] += o[0]; acc[c][1] += o[1]; acc[c][2] += o[2]; acc[c][3] += o[3];
        }
        // C/D layout: col = lane&15, row = (lane>>4)*4 + reg
        const int rbase = blockIdx.x * 64 + rw * 16 + q * 4;
#pragma unroll
        for (int r = 0; r < 4; ++r) {
            const int orow = rbase + r;
            if (orow < N) {
                const float s = dinv[orow];
#pragma unroll
                for (int c = 0; c < CT; ++c)
                    C[(size_t)orow * 96 + c * 16 + m] = (_Float16)(acc[c][r] * s);
            }
        }
    }
}

// ---------------- K=96 GEMMs + fc: bf16 hi/lo A-planes, split-N x2 ----------------
// 512 threads = 8 waves: wave&3 -> rows, wave>>2 -> column half. Disjoint outputs.
template <int M, int K, bool FC>   // FC: +bias, fp32 out; else *dinv, fp16 out
__launch_bounds__(512, 4)
__global__ void mfma_gemm_b(const short* __restrict__ Ahi, const short* __restrict__ Alo,
                            const bf16x8* __restrict__ Whi, const bf16x8* __restrict__ Wlo,
                            const float* __restrict__ bias, const float* __restrict__ dinv,
                            _Float16* __restrict__ Ch, float* __restrict__ Cf, int N) {
    constexpr int CT = M / 16;     // 6 or 4
    constexpr int CTH = CT / 2;    // 3 or 2
    constexpr int KC = K / 32;     // 3
    const int lane = threadIdx.x & 63;
    const int wave = threadIdx.x >> 6;
    const int rw = wave & 3;
    const int c0 = (wave >> 2) * CTH;
    const int q = lane >> 4;
    const int m = lane & 15;
    const int row = blockIdx.x * 64 + rw * 16 + m;
    const int arow = (row < N) ? row : (N - 1);

    f32x4 acc[CTH];
#pragma unroll
    for (int c = 0; c < CTH; ++c) acc[c] = f32x4{0.f, 0.f, 0.f, 0.f};

    const short* ah = Ahi + (size_t)arow * K + q * 8;
    const short* al = Alo + (size_t)arow * K + q * 8;

#pragma unroll
    for (int kc = 0; kc < KC; ++kc) {
        const bf16x8 ahi = *(const bf16x8*)(ah + kc * 32);
        const bf16x8 alo = *(const bf16x8*)(al + kc * 32);
#pragma unroll
        for (int c = 0; c < CTH; ++c) {
            const bf16x8 wh = Whi[(kc * CT + c0 + c) * 64 + lane];
            const bf16x8 wl = Wlo[(kc * CT + c0 + c) * 64 + lane];
            acc[c] = __builtin_amdgcn_mfma_f32_16x16x32_bf16(ahi, wh, acc[c], 0, 0, 0);
            acc[c] = __builtin_amdgcn_mfma_f32_16x16x32_bf16(alo, wh, acc[c], 0, 0, 0);
            acc[c] = __builtin_amdgcn_mfma_f32_16x16x32_bf16(ahi, wl, acc[c], 0, 0, 0);
        }
    }

    const int rbase = blockIdx.x * 64 + rw * 16 + q * 4;
#pragma unroll
    for (int r = 0; r < 4; ++r) {
        const int orow = rbase + r;
        if (orow < N) {
            if (FC) {
#pragma unroll
                for (int c = 0; c < CTH; ++c)
                    Cf[(size_t)orow * M + (c0 + c) * 16 + m] = acc[c][r] + bias[(c0 + c) * 16 + m];
            } else {
                const float s = dinv[orow];
#pragma unroll
                for (int c = 0; c < CTH; ++c)
                    Ch[(size_t)orow * M + (c0 + c) * 16 + m] = (_Float16)(acc[c][r] * s);
            }
        }
    }
}

// ---------------- gather-reduce: fp16 rows in, bf16 hi/lo planes out ----------------
constexpr int TPN = HIDD / 4;  // 24 lanes/node, 4 feats (8 B) each
__launch_bounds__(192)
__global__ void gather_kernel(const int* __restrict__ rowstart, const int* __restrict__ deg,
                              const int* __restrict__ csr_src, const float* __restrict__ dinv,
                              const h4* __restrict__ hs, const float* __restrict__ b,
                              short* __restrict__ outhi, short* __restrict__ outlo) {
    const int t = blockIdx.x * blockDim.x + threadIdx.x;
    const int node = t / TPN;
    const int ci = t % TPN;
    const int c = ci * 4;
    if (node >= NN) return;

    const int r0 = rowstart[node];
    const int d = deg[node];
    const h4* __restrict__ hp = hs + ci;   // row stride = TPN h4's

    const h4 sv = hp[(size_t)node * TPN];  // self-loop
    float4 acc0 = make_float4((float)sv[0], (float)sv[1], (float)sv[2], (float)sv[3]);
    float4 acc1 = make_float4(0.f, 0.f, 0.f, 0.f);
    float4 acc2 = make_float4(0.f, 0.f, 0.f, 0.f);
    float4 acc3 = make_float4(0.f, 0.f, 0.f, 0.f);

    int j = r0;
    const int jend = r0 + d;
    for (; j + 4 <= jend; j += 4) {
        const int s0 = csr_src[j];
        const int s1 = csr_src[j + 1];
        const int s2 = csr_src[j + 2];
        const int s3 = csr_src[j + 3];
        const h4 v0 = hp[(size_t)s0 * TPN];
        const h4 v1 = hp[(size_t)s1 * TPN];
        const h4 v2 = hp[(size_t)s2 * TPN];
        const h4 v3 = hp[(size_t)s3 * TPN];
        acc0.x += (float)v0[0]; acc0.y += (float)v0[1]; acc0.z += (float)v0[2]; acc0.w += (float)v0[3];
        acc1.x += (float)v1[0]; acc1.y += (float)v1[1]; acc1.z += (float)v1[2]; acc1.w += (float)v1[3];
        acc2.x += (float)v2[0]; acc2.y += (float)v2[1]; acc2.z += (float)v2[2]; acc2.w += (float)v2[3];
        acc3.x += (float)v3[0]; acc3.y += (float)v3[1]; acc3.z += (float)v3[2]; acc3.w += (float)v3[3];
    }
    for (; j < jend; ++j) {
        const int s0 = csr_src[j];
        const h4 v0 = hp[(size_t)s0 * TPN];
        acc0.x += (float)v0[0]; acc0.y += (float)v0[1]; acc0.z += (float)v0[2]; acc0.w += (float)v0[3];
    }
    acc0.x += acc1.x; acc0.y += acc1.y; acc0.z += acc1.z; acc0.w += acc1.w;
    acc2.x += acc3.x; acc2.y += acc3.y; acc2.z += acc3.z; acc2.w += acc3.w;
    acc0.x += acc2.x; acc0.y += acc2.y; acc0.z += acc2.z; acc0.w += acc2.w;

    const float di = dinv[node];
    float o[4];
    o[0] = fmaxf(fmaf(di, acc0.x, b[c + 0]), 0.0f);
    o[1] = fmaxf(fmaf(di, acc0.y, b[c + 1]), 0.0f);
    o[2] = fmaxf(fmaf(di, acc0.z, b[c + 2]), 0.0f);
    o[3] = fmaxf(fmaf(di, acc0.w, b[c + 3]), 0.0f);

    short4 hi, lo;
    hi.x = f2bf(o[0]); lo.x = f2bf_trunc(o[0] - bf2f(hi.x));
    hi.y = f2bf(o[1]); lo.y = f2bf_trunc(o[1] - bf2f(hi.y));
    hi.z = f2bf(o[2]); lo.z = f2bf_trunc(o[2] - bf2f(hi.z));
    hi.w = f2bf(o[3]); lo.w = f2bf_trunc(o[3] - bf2f(hi.w));
    *(short4*)(outhi + (size_t)node * HIDD + c) = hi;
    *(short4*)(outlo + (size_t)node * HIDD + c) = lo;
}

extern "C" void kernel_launch(void* const* d_in, const int* in_sizes, int n_in,
                              void* d_out, int out_size, void* d_ws, size_t ws_size,
                              hipStream_t stream) {
    const float* x   = (const float*)d_in[0];
    const int*   ei  = (const int*)d_in[1];
    const float* W0  = (const float*)d_in[2];
    const float* b0  = (const float*)d_in[3];
    const float* W1  = (const float*)d_in[4];
    const float* b1  = (const float*)d_in[5];
    const float* W2  = (const float*)d_in[6];
    const float* b2  = (const float*)d_in[7];
    const float* fcW = (const float*)d_in[8];
    const float* fcb = (const float*)d_in[9];
    float* out = (float*)d_out;

    const int* src = ei;
    const int* dst = ei + NE;

    // workspace layout (float-sized slots, 16B-aligned offsets)
    float* ws = (float*)d_ws;
    float* dinv     = ws;                       // [50000]
    int*   deg      = (int*)(ws + 50176);
    int*   excl     = (int*)(ws + 100352);
    int*   cursor   = (int*)(ws + 150528);
    int*   rowstart = (int*)(ws + 200704);
    int*   partials = (int*)(ws + 250880);      // [256]
    int*   csr_src  = (int*)(ws + 251136);      // [800000]
    short* w0hi = (short*)(ws + 1051392);       // [49152] shorts
    short* w0lo = (short*)(ws + 1075968);
    short* w1hi = (short*)(ws + 1100544);       // [9216] shorts
    short* w1lo = (short*)(ws + 1105152);
    short* w2hi = (short*)(ws + 1109760);
    short* w2lo = (short*)(ws + 1114368);
    short* fchi = (short*)(ws + 1118976);       // [6144] shorts
    short* fclo = (short*)(ws + 1122048);
    _Float16* hs16 = (_Float16*)(ws + 1125120); // [4.8M halves]
    short* Hhi = (short*)(ws + 3525120);        // [4.8M shorts]
    short* Hlo = (short*)(ws + 5925120);        // [4.8M shorts]

    dim3 b256(256);
    const int gN = NBLK;                        // 196
    const int gE = (NE + 255) / 256;            // 3125
    const int gGem = (NN + 63) / 64;            // 782
    const int gGather = (NN * TPN + 191) / 192; // 6250
    const int gPack = (73728 + 255) / 256;      // 288

    // ---- CSR build + dinv + weight pack ----
    zero_int_kernel<<<gN, b256, 0, stream>>>(deg, NN);
    hist_kernel<<<gE, b256, 0, stream>>>(dst, deg);
    scan1_kernel<<<gN, b256, 0, stream>>>(deg, excl, partials);
    scan3_kernel<<<gN, b256, 0, stream>>>(excl, partials, deg, rowstart, dinv, cursor);
    scatter_kernel<<<gE, b256, 0, stream>>>(src, dst, rowstart, cursor, csr_src);
    pack_all<<<gPack, b256, 0, stream>>>(W0, W1, W2, fcW, w0hi, w0lo, w1hi, w1lo,
                                         w2hi, w2lo, fchi, fclo);

    // ---- layer 0 ----
    mfma_gemm_f<KIN><<<gGem, dim3(512), 0, stream>>>(
        x, (const bf16x8*)w0hi, (const bf16x8*)w0lo, dinv, hs16, NN);
    gather_kernel<<<gGather, dim3(192), 0, stream>>>(
        rowstart, deg, csr_src, dinv, (const h4*)hs16, b0, Hhi, Hlo);

    // ---- layer 1 ----
    mfma_gemm_b<HIDD, HIDD, false><<<gGem, dim3(512), 0, stream>>>(
        Hhi, Hlo, (const bf16x8*)w1hi, (const bf16x8*)w1lo, nullptr, dinv, hs16, nullptr, NN);
    gather_kernel<<<gGather, dim3(192), 0, stream>>>(
        rowstart, deg, csr_src, dinv, (const h4*)hs16, b1, Hhi, Hlo);

    // ---- layer 2 ----
    mfma_gemm_b<HIDD, HIDD, false><<<gGem, dim3(512), 0, stream>>>(
        Hhi, Hlo, (const bf16x8*)w2hi, (const bf16x8*)w2lo, nullptr, dinv, hs16, nullptr, NN);
    gather_kernel<<<gGather, dim3(192), 0, stream>>>(
        rowstart, deg, csr_src, dinv, (const h4*)hs16, b2, Hhi, Hlo);

    // ---- fc ----
    mfma_gemm_b<ODIM, HIDD, true><<<gGem, dim3(512), 0, stream>>>(
        Hhi, Hlo, (const bf16x8*)fchi, (const bf16x8*)fclo, fcb, nullptr, nullptr, out, NN);
}

// Round 6
// 401.598 us; speedup vs baseline: 3.0061x; 1.0327x over previous
//
#include <hip/hip_runtime.h>

// GCN r6: (1) gemm_f: split-K x2 + phase-wise LDS staging of W frags (block
// reads W once; ds_read_b128 in loop, no per-wave L2 re-reads);
// (2) gemm_b/fc: whole W hi+lo in LDS; (3) gather: 8-deep load unroll.

constexpr int NN   = 50000;
constexpr int NE   = 800000;
constexpr int KIN  = 512;
constexpr int HIDD = 96;
constexpr int ODIM = 64;
constexpr int NBLK = (NN + 255) / 256;   // 196 scan blocks

typedef short bf16x8 __attribute__((ext_vector_type(8)));
typedef float f32x4  __attribute__((ext_vector_type(4)));
typedef _Float16 h4  __attribute__((ext_vector_type(4)));

__device__ inline short f2bf(float f) {               // RTN-even fp32 -> bf16 bits
    union { float f; unsigned u; } v; v.f = f;
    unsigned r = v.u + 0x7FFFu + ((v.u >> 16) & 1u);
    return (short)(r >> 16);
}
__device__ inline short f2bf_trunc(float f) {         // truncate (for lo residual)
    union { float f; unsigned u; } v; v.f = f;
    return (short)(v.u >> 16);
}
__device__ inline float bf2f(short h) {
    union { unsigned u; float f; } v; v.u = ((unsigned)(unsigned short)h) << 16;
    return v.f;
}

// ---------------- CSR build ----------------
__global__ void zero_int_kernel(int* __restrict__ p, int n) {
    int i = blockIdx.x * blockDim.x + threadIdx.x;
    if (i < n) p[i] = 0;
}

__global__ void hist_kernel(const int* __restrict__ dst, int* __restrict__ deg) {
    int e = blockIdx.x * blockDim.x + threadIdx.x;
    if (e < NE) atomicAdd(&deg[dst[e]], 1);
}

__global__ void scan1_kernel(const int* __restrict__ deg, int* __restrict__ excl,
                             int* __restrict__ partials) {
    __shared__ int tmp[256];
    const int tid = threadIdx.x;
    const int i = blockIdx.x * 256 + tid;
    const int v = (i < NN) ? deg[i] : 0;
    tmp[tid] = v;
    __syncthreads();
#pragma unroll
    for (int off = 1; off < 256; off <<= 1) {
        int t = (tid >= off) ? tmp[tid - off] : 0;
        __syncthreads();
        tmp[tid] += t;
        __syncthreads();
    }
    if (i < NN) excl[i] = tmp[tid] - v;
    if (tid == 255) partials[blockIdx.x] = tmp[tid];
}

__global__ void scan3_kernel(const int* __restrict__ excl, const int* __restrict__ partials,
                             const int* __restrict__ deg, int* __restrict__ rowstart,
                             float* __restrict__ dinv, int* __restrict__ cursor) {
    __shared__ int tmp[256];
    const int tid = threadIdx.x;
    tmp[tid] = (tid < (int)blockIdx.x) ? partials[tid] : 0;   // NBLK=196 <= 256
    __syncthreads();
#pragma unroll
    for (int off = 128; off > 0; off >>= 1) {
        if (tid < off) tmp[tid] += tmp[tid + off];
        __syncthreads();
    }
    const int boff = tmp[0];
    const int i = blockIdx.x * 256 + tid;
    if (i < NN) {
        rowstart[i] = excl[i] + boff;
        dinv[i] = 1.0f / sqrtf((float)deg[i] + 1.0f);
        cursor[i] = 0;
    }
}

__global__ void scatter_kernel(const int* __restrict__ src, const int* __restrict__ dst,
                               const int* __restrict__ rowstart, int* __restrict__ cursor,
                               int* __restrict__ csr_src) {
    int e = blockIdx.x * blockDim.x + threadIdx.x;
    if (e < NE) {
        const int d = dst[e];
        const int pos = rowstart[d] + atomicAdd(&cursor[d], 1);
        csr_src[pos] = src[e];
    }
}

// ---------------- fused W hi/lo pack (MFMA B-frag order) ----------------
__global__ void pack_all(const float* __restrict__ W0, const float* __restrict__ W1,
                         const float* __restrict__ W2, const float* __restrict__ FC,
                         short* __restrict__ w0hi, short* __restrict__ w0lo,
                         short* __restrict__ w1hi, short* __restrict__ w1lo,
                         short* __restrict__ w2hi, short* __restrict__ w2lo,
                         short* __restrict__ fchi, short* __restrict__ fclo) {
    const int idx = blockIdx.x * 256 + threadIdx.x;
    const float* W; short *hi, *lo; int M, li;
    if      (idx < 49152) { W = W0; hi = w0hi; lo = w0lo; M = 96; li = idx; }
    else if (idx < 58368) { W = W1; hi = w1hi; lo = w1lo; M = 96; li = idx - 49152; }
    else if (idx < 67584) { W = W2; hi = w2hi; lo = w2lo; M = 96; li = idx - 58368; }
    else if (idx < 73728) { W = FC; hi = fchi; lo = fclo; M = 64; li = idx - 67584; }
    else return;
    const int CT = M >> 4;
    const int j = li & 7;
    const int lane = (li >> 3) & 63;
    const int t = li >> 9;             // kc*CT + ct
    const int ct = t % CT;
    const int kc = t / CT;
    const int k = kc * 32 + (lane >> 4) * 8 + j;
    const int n = ct * 16 + (lane & 15);
    const float w = W[k * M + n];
    const short h = f2bf(w);
    hi[li] = h;
    lo[li] = f2bf_trunc(w - bf2f(h));
}

// ---------------- layer-0 GEMM: fp32 A, split-bf16, split-K x2, LDS-staged W ----
// 512 thr = 8 waves: wave&3 -> row group (16 rows of 64), wave>>2 -> K half.
// Phases stage 2 kc per K-half (4 kc-groups, 48 KB) into LDS cooperatively.
template <int K>   // 512
__launch_bounds__(512, 6)
__global__ void mfma_gemm_f(const float* __restrict__ A, const short* __restrict__ Whi,
                            const short* __restrict__ Wlo, const float* __restrict__ dinv,
                            _Float16* __restrict__ C, int N) {
    constexpr int CT = 6;
    constexpr int KCH = K / 64;        // kc per half = 8
    constexpr int PH  = KCH / 2;       // 4 phases, 2 kc per half per phase
    // per kc-group: CT*64*8 = 3072 shorts (6 KB). 4 groups staged: slots [kh*2+kc]
    __shared__ short sHi[4 * 3072];    // 24 KB
    __shared__ short sLo[4 * 3072];    // 24 KB

    const int tid = threadIdx.x;
    const int lane = tid & 63;
    const int wave = tid >> 6;
    const int rw = wave & 3;
    const int kh = wave >> 2;
    const int q = lane >> 4;
    const int m = lane & 15;
    const int row = blockIdx.x * 64 + rw * 16 + m;
    const int arow = (row < N) ? row : (N - 1);

    f32x4 acc[CT];
#pragma unroll
    for (int c = 0; c < CT; ++c) acc[c] = f32x4{0.f, 0.f, 0.f, 0.f};

    const float* ap = A + (size_t)arow * K + kh * (K / 2) + q * 8;
    float4 a0 = *(const float4*)(ap);
    float4 a1 = *(const float4*)(ap + 4);

#pragma unroll
    for (int p = 0; p < PH; ++p) {
        // ---- stage 4 kc-groups: {p*2, p*2+1} for each half ----
        // 4*3072 shorts = 1536 float4 chunks; 512 threads x 3
#pragma unroll
        for (int i = 0; i < 3; ++i) {
            const int ci = i * 512 + tid;            // 0..1535
            const int slot = ci / 384;               // 384 f4 per group
            const int within = ci - slot * 384;
            const int kcg = (slot >> 1) * KCH + p * 2 + (slot & 1);
            const int so = kcg * 3072 + within * 8;
            const int doff = ci * 8;
            *(float4*)(sHi + doff) = *(const float4*)(Whi + so);
            *(float4*)(sLo + doff) = *(const float4*)(Wlo + so);
        }
        __syncthreads();

#pragma unroll
        for (int kc = 0; kc < 2; ++kc) {
            // convert current A
            const float af[8] = {a0.x, a0.y, a0.z, a0.w, a1.x, a1.y, a1.z, a1.w};
            bf16x8 ahi, alo;
#pragma unroll
            for (int j = 0; j < 8; ++j) {
                const short h = f2bf(af[j]);
                ahi[j] = h;
                alo[j] = f2bf_trunc(af[j] - bf2f(h));
            }
            // prefetch next A
            if (p * 2 + kc + 1 < KCH) {
                ap += 32;
                a0 = *(const float4*)(ap);
                a1 = *(const float4*)(ap + 4);
            }
            const int slot = kh * 2 + kc;
            const short* hbase = sHi + slot * 3072 + lane * 8;
            const short* lbase = sLo + slot * 3072 + lane * 8;
#pragma unroll
            for (int c = 0; c < CT; ++c) {
                const bf16x8 wh = *(const bf16x8*)(hbase + c * 512);
                const bf16x8 wl = *(const bf16x8*)(lbase + c * 512);
                acc[c] = __builtin_amdgcn_mfma_f32_16x16x32_bf16(ahi, wh, acc[c], 0, 0, 0);
                acc[c] = __builtin_amdgcn_mfma_f32_16x16x32_bf16(alo, wh, acc[c], 0, 0, 0);
                acc[c] = __builtin_amdgcn_mfma_f32_16x16x32_bf16(ahi, wl, acc[c], 0, 0, 0);
            }
        }
        __syncthreads();
    }

    // ---- split-K combine via LDS (reuse staging buffers: 24 KB needed) ----
    float* sAcc = (float*)sHi;    // 4 rw * 64 lanes * 6 ct * 4 = 6144 floats = 24 KB
    if (kh == 1) {
#pragma unroll
        for (int c = 0; c < CT; ++c)
            *(f32x4*)(sAcc + ((rw * 64 + lane) * CT + c) * 4) = acc[c];
    }
    __syncthreads();
    if (kh == 0) {
#pragma unroll
        for (int c = 0; c < CT; ++c) {
            const f32x4 o = *(const f32x4*)(sAcc + ((rw * 64 + lane) * CT + c) * 4);
            acc[c][0] += o[0]; acc[c][1] += o[1]; acc[c][2] += o[2]; acc[c][3] += o[3];
        }
        // C/D layout: col = lane&15, row = (lane>>4)*4 + reg
        const int rbase = blockIdx.x * 64 + rw * 16 + q * 4;
#pragma unroll
        for (int r = 0; r < 4; ++r) {
            const int orow = rbase + r;
            if (orow < N) {
                const float s = dinv[orow];
#pragma unroll
                for (int c = 0; c < CT; ++c)
                    C[(size_t)orow * 96 + c * 16 + m] = (_Float16)(acc[c][r] * s);
            }
        }
    }
}

// ---------------- K=96 GEMMs + fc: bf16 hi/lo A-planes, split-N x2, LDS W ----
template <int M, int K, bool FC>   // FC: +bias, fp32 out; else *dinv, fp16 out
__launch_bounds__(512, 6)
__global__ void mfma_gemm_b(const short* __restrict__ Ahi, const short* __restrict__ Alo,
                            const short* __restrict__ Whi, const short* __restrict__ Wlo,
                            const float* __restrict__ bias, const float* __restrict__ dinv,
                            _Float16* __restrict__ Ch, float* __restrict__ Cf, int N) {
    constexpr int CT = M / 16;     // 6 or 4
    constexpr int CTH = CT / 2;    // 3 or 2
    constexpr int KC = K / 32;     // 3
    constexpr int WSH = KC * CT * 512;   // shorts per plane
    __shared__ short sHi[WSH];
    __shared__ short sLo[WSH];

    const int tid = threadIdx.x;
    // stage whole W hi+lo
    for (int i = tid; i < WSH / 8; i += 512) {
        *(float4*)(sHi + i * 8) = *(const float4*)(Whi + i * 8);
        *(float4*)(sLo + i * 8) = *(const float4*)(Wlo + i * 8);
    }

    const int lane = tid & 63;
    const int wave = tid >> 6;
    const int rw = wave & 3;
    const int c0 = (wave >> 2) * CTH;
    const int q = lane >> 4;
    const int m = lane & 15;
    const int row = blockIdx.x * 64 + rw * 16 + m;
    const int arow = (row < N) ? row : (N - 1);

    // preload all A frags (6 x 16B, independent)
    const short* ah = Ahi + (size_t)arow * K + q * 8;
    const short* al = Alo + (size_t)arow * K + q * 8;
    bf16x8 Ah[KC], Al[KC];
#pragma unroll
    for (int kc = 0; kc < KC; ++kc) {
        Ah[kc] = *(const bf16x8*)(ah + kc * 32);
        Al[kc] = *(const bf16x8*)(al + kc * 32);
    }

    f32x4 acc[CTH];
#pragma unroll
    for (int c = 0; c < CTH; ++c) acc[c] = f32x4{0.f, 0.f, 0.f, 0.f};

    __syncthreads();

#pragma unroll
    for (int kc = 0; kc < KC; ++kc) {
#pragma unroll
        for (int c = 0; c < CTH; ++c) {
            const int fo = ((kc * CT + c0 + c) * 64 + lane) * 8;
            const bf16x8 wh = *(const bf16x8*)(sHi + fo);
            const bf16x8 wl = *(const bf16x8*)(sLo + fo);
            acc[c] = __builtin_amdgcn_mfma_f32_16x16x32_bf16(Ah[kc], wh, acc[c], 0, 0, 0);
            acc[c] = __builtin_amdgcn_mfma_f32_16x16x32_bf16(Al[kc], wh, acc[c], 0, 0, 0);
            acc[c] = __builtin_amdgcn_mfma_f32_16x16x32_bf16(Ah[kc], wl, acc[c], 0, 0, 0);
        }
    }

    const int rbase = blockIdx.x * 64 + rw * 16 + q * 4;
#pragma unroll
    for (int r = 0; r < 4; ++r) {
        const int orow = rbase + r;
        if (orow < N) {
            if (FC) {
#pragma unroll
                for (int c = 0; c < CTH; ++c)
                    Cf[(size_t)orow * M + (c0 + c) * 16 + m] = acc[c][r] + bias[(c0 + c) * 16 + m];
            } else {
                const float s = dinv[orow];
#pragma unroll
                for (int c = 0; c < CTH; ++c)
                    Ch[(size_t)orow * M + (c0 + c) * 16 + m] = (_Float16)(acc[c][r] * s);
            }
        }
    }
}

// ---------------- gather-reduce: fp16 rows in, bf16 hi/lo planes out ----------------
constexpr int TPN = HIDD / 4;  // 24 lanes/node, 4 feats (8 B) each
__launch_bounds__(192)
__global__ void gather_kernel(const int* __restrict__ rowstart, const int* __restrict__ deg,
                              const int* __restrict__ csr_src, const float* __restrict__ dinv,
                              const h4* __restrict__ hs, const float* __restrict__ b,
                              short* __restrict__ outhi, short* __restrict__ outlo) {
    const int t = blockIdx.x * blockDim.x + threadIdx.x;
    const int node = t / TPN;
    const int ci = t % TPN;
    const int c = ci * 4;
    if (node >= NN) return;

    const int r0 = rowstart[node];
    const int d = deg[node];
    const h4* __restrict__ hp = hs + ci;   // row stride = TPN h4's

    const h4 sv = hp[(size_t)node * TPN];  // self-loop
    float4 acc0 = make_float4((float)sv[0], (float)sv[1], (float)sv[2], (float)sv[3]);
    float4 acc1 = make_float4(0.f, 0.f, 0.f, 0.f);
    float4 acc2 = make_float4(0.f, 0.f, 0.f, 0.f);
    float4 acc3 = make_float4(0.f, 0.f, 0.f, 0.f);

    int j = r0;
    const int jend = r0 + d;
    for (; j + 8 <= jend; j += 8) {
        int s[8];
#pragma unroll
        for (int i = 0; i < 8; ++i) s[i] = csr_src[j + i];
        h4 v[8];
#pragma unroll
        for (int i = 0; i < 8; ++i) v[i] = hp[(size_t)s[i] * TPN];
        acc0.x += (float)v[0][0] + (float)v[4][0]; acc0.y += (float)v[0][1] + (float)v[4][1];
        acc0.z += (float)v[0][2] + (float)v[4][2]; acc0.w += (float)v[0][3] + (float)v[4][3];
        acc1.x += (float)v[1][0] + (float)v[5][0]; acc1.y += (float)v[1][1] + (float)v[5][1];
        acc1.z += (float)v[1][2] + (float)v[5][2]; acc1.w += (float)v[1][3] + (float)v[5][3];
        acc2.x += (float)v[2][0] + (float)v[6][0]; acc2.y += (float)v[2][1] + (float)v[6][1];
        acc2.z += (float)v[2][2] + (float)v[6][2]; acc2.w += (float)v[2][3] + (float)v[6][3];
        acc3.x += (float)v[3][0] + (float)v[7][0]; acc3.y += (float)v[3][1] + (float)v[7][1];
        acc3.z += (float)v[3][2] + (float)v[7][2]; acc3.w += (float)v[3][3] + (float)v[7][3];
    }
    for (; j < jend; ++j) {
        const h4 v0 = hp[(size_t)csr_src[j] * TPN];
        acc0.x += (float)v0[0]; acc0.y += (float)v0[1]; acc0.z += (float)v0[2]; acc0.w += (float)v0[3];
    }
    acc0.x += acc1.x + acc2.x + acc3.x;
    acc0.y += acc1.y + acc2.y + acc3.y;
    acc0.z += acc1.z + acc2.z + acc3.z;
    acc0.w += acc1.w + acc2.w + acc3.w;

    const float di = dinv[node];
    float o[4];
    o[0] = fmaxf(fmaf(di, acc0.x, b[c + 0]), 0.0f);
    o[1] = fmaxf(fmaf(di, acc0.y, b[c + 1]), 0.0f);
    o[2] = fmaxf(fmaf(di, acc0.z, b[c + 2]), 0.0f);
    o[3] = fmaxf(fmaf(di, acc0.w, b[c + 3]), 0.0f);

    short4 hi, lo;
    hi.x = f2bf(o[0]); lo.x = f2bf_trunc(o[0] - bf2f(hi.x));
    hi.y = f2bf(o[1]); lo.y = f2bf_trunc(o[1] - bf2f(hi.y));
    hi.z = f2bf(o[2]); lo.z = f2bf_trunc(o[2] - bf2f(hi.z));
    hi.w = f2bf(o[3]); lo.w = f2bf_trunc(o[3] - bf2f(hi.w));
    *(short4*)(outhi + (size_t)node * HIDD + c) = hi;
    *(short4*)(outlo + (size_t)node * HIDD + c) = lo;
}

extern "C" void kernel_launch(void* const* d_in, const int* in_sizes, int n_in,
                              void* d_out, int out_size, void* d_ws, size_t ws_size,
                              hipStream_t stream) {
    const float* x   = (const float*)d_in[0];
    const int*   ei  = (const int*)d_in[1];
    const float* W0  = (const float*)d_in[2];
    const float* b0  = (const float*)d_in[3];
    const float* W1  = (const float*)d_in[4];
    const float* b1  = (const float*)d_in[5];
    const float* W2  = (const float*)d_in[6];
    const float* b2  = (const float*)d_in[7];
    const float* fcW = (const float*)d_in[8];
    const float* fcb = (const float*)d_in[9];
    float* out = (float*)d_out;

    const int* src = ei;
    const int* dst = ei + NE;

    float* ws = (float*)d_ws;
    float* dinv     = ws;                       // [50000]
    int*   deg      = (int*)(ws + 50176);
    int*   excl     = (int*)(ws + 100352);
    int*   cursor   = (int*)(ws + 150528);
    int*   rowstart = (int*)(ws + 200704);
    int*   partials = (int*)(ws + 250880);      // [256]
    int*   csr_src  = (int*)(ws + 251136);      // [800000]
    short* w0hi = (short*)(ws + 1051392);       // [49152] shorts
    short* w0lo = (short*)(ws + 1075968);
    short* w1hi = (short*)(ws + 1100544);       // [9216] shorts
    short* w1lo = (short*)(ws + 1105152);
    short* w2hi = (short*)(ws + 1109760);
    short* w2lo = (short*)(ws + 1114368);
    short* fchi = (short*)(ws + 1118976);       // [6144] shorts
    short* fclo = (short*)(ws + 1122048);
    _Float16* hs16 = (_Float16*)(ws + 1125120); // [4.8M halves]
    short* Hhi = (short*)(ws + 3525120);        // [4.8M shorts]
    short* Hlo = (short*)(ws + 5925120);        // [4.8M shorts]

    dim3 b256(256);
    const int gN = NBLK;                        // 196
    const int gE = (NE + 255) / 256;            // 3125
    const int gGem = (NN + 63) / 64;            // 782
    const int gGather = (NN * TPN + 191) / 192; // 6250
    const int gPack = (73728 + 255) / 256;      // 288

    // ---- CSR build + dinv + weight pack ----
    zero_int_kernel<<<gN, b256, 0, stream>>>(deg, NN);
    hist_kernel<<<gE, b256, 0, stream>>>(dst, deg);
    scan1_kernel<<<gN, b256, 0, stream>>>(deg, excl, partials);
    scan3_kernel<<<gN, b256, 0, stream>>>(excl, partials, deg, rowstart, dinv, cursor);
    scatter_kernel<<<gE, b256, 0, stream>>>(src, dst, rowstart, cursor, csr_src);
    pack_all<<<gPack, b256, 0, stream>>>(W0, W1, W2, fcW, w0hi, w0lo, w1hi, w1lo,
                                         w2hi, w2lo, fchi, fclo);

    // ---- layer 0 ----
    mfma_gemm_f<KIN><<<gGem, dim3(512), 0, stream>>>(
        x, w0hi, w0lo, dinv, hs16, NN);
    gather_kernel<<<gGather, dim3(192), 0, stream>>>(
        rowstart, deg, csr_src, dinv, (const h4*)hs16, b0, Hhi, Hlo);

    // ---- layer 1 ----
    mfma_gemm_b<HIDD, HIDD, false><<<gGem, dim3(512), 0, stream>>>(
        Hhi, Hlo, w1hi, w1lo, nullptr, dinv, hs16, nullptr, NN);
    gather_kernel<<<gGather, dim3(192), 0, stream>>>(
        rowstart, deg, csr_src, dinv, (const h4*)hs16, b1, Hhi, Hlo);

    // ---- layer 2 ----
    mfma_gemm_b<HIDD, HIDD, false><<<gGem, dim3(512), 0, stream>>>(
        Hhi, Hlo, w2hi, w2lo, nullptr, dinv, hs16, nullptr, NN);
    gather_kernel<<<gGather, dim3(192), 0, stream>>>(
        rowstart, deg, csr_src, dinv, (const h4*)hs16, b2, Hhi, Hlo);

    // ---- fc ----
    mfma_gemm_b<ODIM, HIDD, true><<<gGem, dim3(512), 0, stream>>>(
        Hhi, Hlo, fchi, fclo, fcb, nullptr, nullptr, out, NN);
}

// Round 7
// 377.846 us; speedup vs baseline: 3.1951x; 1.0629x over previous
//
#include <hip/hip_runtime.h>

// GCN r7: fuse gather+GEMM per layer. Block = 64 nodes: gather (8 lanes x 12
// feats/node) -> relu/bias/dinv -> split-bf16 tile in LDS -> MFMA GEMM with
// next layer's W (frags from L2). Removes Hhi/Hlo HBM round-trip + 3 launches.

constexpr int NN   = 50000;
constexpr int NE   = 800000;
constexpr int KIN  = 512;
constexpr int HIDD = 96;
constexpr int ODIM = 64;
constexpr int NBLK = (NN + 255) / 256;   // 196 scan blocks

typedef short bf16x8 __attribute__((ext_vector_type(8)));
typedef float f32x4  __attribute__((ext_vector_type(4)));
typedef _Float16 h4  __attribute__((ext_vector_type(4)));

__device__ inline short f2bf(float f) {               // RTN-even fp32 -> bf16 bits
    union { float f; unsigned u; } v; v.f = f;
    unsigned r = v.u + 0x7FFFu + ((v.u >> 16) & 1u);
    return (short)(r >> 16);
}
__device__ inline short f2bf_trunc(float f) {         // truncate (for lo residual)
    union { float f; unsigned u; } v; v.f = f;
    return (short)(v.u >> 16);
}
__device__ inline float bf2f(short h) {
    union { unsigned u; float f; } v; v.u = ((unsigned)(unsigned short)h) << 16;
    return v.f;
}

// ---------------- CSR build ----------------
__global__ void zero_int_kernel(int* __restrict__ p, int n) {
    int i = blockIdx.x * blockDim.x + threadIdx.x;
    if (i < n) p[i] = 0;
}

__global__ void hist_kernel(const int* __restrict__ dst, int* __restrict__ deg) {
    int e = blockIdx.x * blockDim.x + threadIdx.x;
    if (e < NE) atomicAdd(&deg[dst[e]], 1);
}

__global__ void scan1_kernel(const int* __restrict__ deg, int* __restrict__ excl,
                             int* __restrict__ partials) {
    __shared__ int tmp[256];
    const int tid = threadIdx.x;
    const int i = blockIdx.x * 256 + tid;
    const int v = (i < NN) ? deg[i] : 0;
    tmp[tid] = v;
    __syncthreads();
#pragma unroll
    for (int off = 1; off < 256; off <<= 1) {
        int t = (tid >= off) ? tmp[tid - off] : 0;
        __syncthreads();
        tmp[tid] += t;
        __syncthreads();
    }
    if (i < NN) excl[i] = tmp[tid] - v;
    if (tid == 255) partials[blockIdx.x] = tmp[tid];
}

__global__ void scan3_kernel(const int* __restrict__ excl, const int* __restrict__ partials,
                             const int* __restrict__ deg, int* __restrict__ rowstart,
                             float* __restrict__ dinv, int* __restrict__ cursor) {
    __shared__ int tmp[256];
    const int tid = threadIdx.x;
    tmp[tid] = (tid < (int)blockIdx.x) ? partials[tid] : 0;   // NBLK=196 <= 256
    __syncthreads();
#pragma unroll
    for (int off = 128; off > 0; off >>= 1) {
        if (tid < off) tmp[tid] += tmp[tid + off];
        __syncthreads();
    }
    const int boff = tmp[0];
    const int i = blockIdx.x * 256 + tid;
    if (i < NN) {
        rowstart[i] = excl[i] + boff;
        dinv[i] = 1.0f / sqrtf((float)deg[i] + 1.0f);
        cursor[i] = 0;
    }
}

__global__ void scatter_kernel(const int* __restrict__ src, const int* __restrict__ dst,
                               const int* __restrict__ rowstart, int* __restrict__ cursor,
                               int* __restrict__ csr_src) {
    int e = blockIdx.x * blockDim.x + threadIdx.x;
    if (e < NE) {
        const int d = dst[e];
        const int pos = rowstart[d] + atomicAdd(&cursor[d], 1);
        csr_src[pos] = src[e];
    }
}

// ---------------- fused W hi/lo pack (MFMA B-frag order) ----------------
__global__ void pack_all(const float* __restrict__ W0, const float* __restrict__ W1,
                         const float* __restrict__ W2, const float* __restrict__ FC,
                         short* __restrict__ w0hi, short* __restrict__ w0lo,
                         short* __restrict__ w1hi, short* __restrict__ w1lo,
                         short* __restrict__ w2hi, short* __restrict__ w2lo,
                         short* __restrict__ fchi, short* __restrict__ fclo) {
    const int idx = blockIdx.x * 256 + threadIdx.x;
    const float* W; short *hi, *lo; int M, li;
    if      (idx < 49152) { W = W0; hi = w0hi; lo = w0lo; M = 96; li = idx; }
    else if (idx < 58368) { W = W1; hi = w1hi; lo = w1lo; M = 96; li = idx - 49152; }
    else if (idx < 67584) { W = W2; hi = w2hi; lo = w2lo; M = 96; li = idx - 58368; }
    else if (idx < 73728) { W = FC; hi = fchi; lo = fclo; M = 64; li = idx - 67584; }
    else return;
    const int CT = M >> 4;
    const int j = li & 7;
    const int lane = (li >> 3) & 63;
    const int t = li >> 9;             // kc*CT + ct
    const int ct = t % CT;
    const int kc = t / CT;
    const int k = kc * 32 + (lane >> 4) * 8 + j;
    const int n = ct * 16 + (lane & 15);
    const float w = W[k * M + n];
    const short h = f2bf(w);
    hi[li] = h;
    lo[li] = f2bf_trunc(w - bf2f(h));
}

// ---------------- layer-0 GEMM: fp32 A, split-bf16, split-K x2, LDS-staged W ----
template <int K>   // 512
__launch_bounds__(512, 6)
__global__ void mfma_gemm_f(const float* __restrict__ A, const short* __restrict__ Whi,
                            const short* __restrict__ Wlo, const float* __restrict__ dinv,
                            _Float16* __restrict__ C, int N) {
    constexpr int CT = 6;
    constexpr int KCH = K / 64;        // kc per half = 8
    constexpr int PH  = KCH / 2;       // 4 phases, 2 kc per half per phase
    __shared__ short sHi[4 * 3072];    // 24 KB
    __shared__ short sLo[4 * 3072];    // 24 KB

    const int tid = threadIdx.x;
    const int lane = tid & 63;
    const int wave = tid >> 6;
    const int rw = wave & 3;
    const int kh = wave >> 2;
    const int q = lane >> 4;
    const int m = lane & 15;
    const int row = blockIdx.x * 64 + rw * 16 + m;
    const int arow = (row < N) ? row : (N - 1);

    f32x4 acc[CT];
#pragma unroll
    for (int c = 0; c < CT; ++c) acc[c] = f32x4{0.f, 0.f, 0.f, 0.f};

    const float* ap = A + (size_t)arow * K + kh * (K / 2) + q * 8;
    float4 a0 = *(const float4*)(ap);
    float4 a1 = *(const float4*)(ap + 4);

#pragma unroll
    for (int p = 0; p < PH; ++p) {
#pragma unroll
        for (int i = 0; i < 3; ++i) {
            const int ci = i * 512 + tid;            // 0..1535
            const int slot = ci / 384;               // 384 f4 per group
            const int within = ci - slot * 384;
            const int kcg = (slot >> 1) * KCH + p * 2 + (slot & 1);
            const int so = kcg * 3072 + within * 8;
            const int doff = ci * 8;
            *(float4*)(sHi + doff) = *(const float4*)(Whi + so);
            *(float4*)(sLo + doff) = *(const float4*)(Wlo + so);
        }
        __syncthreads();

#pragma unroll
        for (int kc = 0; kc < 2; ++kc) {
            const float af[8] = {a0.x, a0.y, a0.z, a0.w, a1.x, a1.y, a1.z, a1.w};
            bf16x8 ahi, alo;
#pragma unroll
            for (int j = 0; j < 8; ++j) {
                const short h = f2bf(af[j]);
                ahi[j] = h;
                alo[j] = f2bf_trunc(af[j] - bf2f(h));
            }
            if (p * 2 + kc + 1 < KCH) {
                ap += 32;
                a0 = *(const float4*)(ap);
                a1 = *(const float4*)(ap + 4);
            }
            const int slot = kh * 2 + kc;
            const short* hbase = sHi + slot * 3072 + lane * 8;
            const short* lbase = sLo + slot * 3072 + lane * 8;
#pragma unroll
            for (int c = 0; c < CT; ++c) {
                const bf16x8 wh = *(const bf16x8*)(hbase + c * 512);
                const bf16x8 wl = *(const bf16x8*)(lbase + c * 512);
                acc[c] = __builtin_amdgcn_mfma_f32_16x16x32_bf16(ahi, wh, acc[c], 0, 0, 0);
                acc[c] = __builtin_amdgcn_mfma_f32_16x16x32_bf16(alo, wh, acc[c], 0, 0, 0);
                acc[c] = __builtin_amdgcn_mfma_f32_16x16x32_bf16(ahi, wl, acc[c], 0, 0, 0);
            }
        }
        __syncthreads();
    }

    // split-K combine via LDS (reuse staging buffers)
    float* sAcc = (float*)sHi;
    if (kh == 1) {
#pragma unroll
        for (int c = 0; c < CT; ++c)
            *(f32x4*)(sAcc + ((rw * 64 + lane) * CT + c) * 4) = acc[c];
    }
    __syncthreads();
    if (kh == 0) {
#pragma unroll
        for (int c = 0; c < CT; ++c) {
            const f32x4 o = *(const f32x4*)(sAcc + ((rw * 64 + lane) * CT + c) * 4);
            acc[c][0] += o[0]; acc[c][1] += o[1]; acc[c][2] += o[2]; acc[c][3] += o[3];
        }
        const int rbase = blockIdx.x * 64 + rw * 16 + q * 4;
#pragma unroll
        for (int r = 0; r < 4; ++r) {
            const int orow = rbase + r;
            if (orow < N) {
                const float s = dinv[orow];
#pragma unroll
                for (int c = 0; c < CT; ++c)
                    C[(size_t)orow * 96 + c * 16 + m] = (_Float16)(acc[c][r] * s);
            }
        }
    }
}

// ---------------- fused gather + GEMM ----------------
// Phase 1 (gather): 512 thr = 64 nodes x 8 lanes; lane owns 12 feats (24 B).
//   h[i,f] = relu(dinv[i]*(sum_src hs[src,f] + hs[i,f]) + gb[f]) -> split-bf16 in LDS.
// Phase 2 (GEMM): hs' = (h @ W)*dinv (fp16) or out = h @ W + bias2 (fp32, FC).
constexpr int APAD = 104;   // LDS row stride in shorts (52 words: 2-way-free for b128)
template <int M, bool FC>
__launch_bounds__(512, 6)
__global__ void fused_gg(const int* __restrict__ rowstart, const int* __restrict__ deg,
                         const int* __restrict__ csr_src, const float* __restrict__ dinv,
                         const h4* __restrict__ hs, const float* __restrict__ gb,
                         const short* __restrict__ Whi, const short* __restrict__ Wlo,
                         const float* __restrict__ bias2,
                         _Float16* __restrict__ Ch, float* __restrict__ Cf, int N) {
    constexpr int CT = M / 16;     // 6 or 4
    constexpr int CTH = CT / 2;    // 3 or 2
    __shared__ short sAhi[64 * APAD];
    __shared__ short sAlo[64 * APAD];

    const int tid = threadIdx.x;
    const int nl = tid >> 3;            // node in tile 0..63
    const int f8 = tid & 7;             // feat chunk: [f8*12, f8*12+12)
    const int node = blockIdx.x * 64 + nl;
    const bool valid = node < N;

    float acc[12];
#pragma unroll
    for (int i = 0; i < 12; ++i) acc[i] = 0.0f;

    if (valid) {
        const h4* __restrict__ hp = hs + (size_t)node * 24 + f8 * 3;
        // self-loop
        {
            const h4 s0 = hp[0], s1 = hp[1], s2 = hp[2];
#pragma unroll
            for (int e = 0; e < 4; ++e) {
                acc[e] += (float)s0[e]; acc[4 + e] += (float)s1[e]; acc[8 + e] += (float)s2[e];
            }
        }
        int j = rowstart[node];
        const int jend = j + deg[node];
        for (; j + 4 <= jend; j += 4) {
            int s[4];
#pragma unroll
            for (int i = 0; i < 4; ++i) s[i] = csr_src[j + i];
            h4 v[4][3];
#pragma unroll
            for (int i = 0; i < 4; ++i) {
                const h4* __restrict__ p = hs + (size_t)s[i] * 24 + f8 * 3;
                v[i][0] = p[0]; v[i][1] = p[1]; v[i][2] = p[2];
            }
#pragma unroll
            for (int i = 0; i < 4; ++i)
#pragma unroll
                for (int e = 0; e < 4; ++e) {
                    acc[e] += (float)v[i][0][e];
                    acc[4 + e] += (float)v[i][1][e];
                    acc[8 + e] += (float)v[i][2][e];
                }
        }
        for (; j < jend; ++j) {
            const h4* __restrict__ p = hs + (size_t)csr_src[j] * 24 + f8 * 3;
            const h4 v0 = p[0], v1 = p[1], v2 = p[2];
#pragma unroll
            for (int e = 0; e < 4; ++e) {
                acc[e] += (float)v0[e]; acc[4 + e] += (float)v1[e]; acc[8 + e] += (float)v2[e];
            }
        }
        const float di = dinv[node];
        short4 hi[3], lo[3];
#pragma unroll
        for (int t = 0; t < 3; ++t) {
#pragma unroll
            for (int e = 0; e < 4; ++e) {
                const float o = fmaxf(fmaf(di, acc[t * 4 + e], gb[f8 * 12 + t * 4 + e]), 0.0f);
                const short h = f2bf(o);
                ((short*)&hi[t])[e] = h;
                ((short*)&lo[t])[e] = f2bf_trunc(o - bf2f(h));
            }
        }
        short* dh = sAhi + nl * APAD + f8 * 12;
        short* dl = sAlo + nl * APAD + f8 * 12;
#pragma unroll
        for (int t = 0; t < 3; ++t) {
            *(short4*)(dh + t * 4) = hi[t];
            *(short4*)(dl + t * 4) = lo[t];
        }
    } else {
        short* dh = sAhi + nl * APAD + f8 * 12;
        short* dl = sAlo + nl * APAD + f8 * 12;
        const short4 z = {0, 0, 0, 0};
#pragma unroll
        for (int t = 0; t < 3; ++t) { *(short4*)(dh + t * 4) = z; *(short4*)(dl + t * 4) = z; }
    }
    __syncthreads();

    // ---- GEMM phase: 8 waves = 4 row groups x 2 column halves ----
    const int lane = tid & 63;
    const int wave = tid >> 6;
    const int rw = wave & 3;
    const int c0 = (wave >> 2) * CTH;
    const int q = lane >> 4;
    const int m = lane & 15;

    bf16x8 Ah[3], Al[3];
#pragma unroll
    for (int kc = 0; kc < 3; ++kc) {
        const int off = (rw * 16 + m) * APAD + kc * 32 + q * 8;
        Ah[kc] = *(const bf16x8*)(sAhi + off);
        Al[kc] = *(const bf16x8*)(sAlo + off);
    }

    f32x4 gacc[CTH];
#pragma unroll
    for (int c = 0; c < CTH; ++c) gacc[c] = f32x4{0.f, 0.f, 0.f, 0.f};

#pragma unroll
    for (int kc = 0; kc < 3; ++kc) {
#pragma unroll
        for (int c = 0; c < CTH; ++c) {
            const int fo = ((kc * CT + c0 + c) * 64 + lane) * 8;
            const bf16x8 wh = *(const bf16x8*)(Whi + fo);
            const bf16x8 wl = *(const bf16x8*)(Wlo + fo);
            gacc[c] = __builtin_amdgcn_mfma_f32_16x16x32_bf16(Ah[kc], wh, gacc[c], 0, 0, 0);
            gacc[c] = __builtin_amdgcn_mfma_f32_16x16x32_bf16(Al[kc], wh, gacc[c], 0, 0, 0);
            gacc[c] = __builtin_amdgcn_mfma_f32_16x16x32_bf16(Ah[kc], wl, gacc[c], 0, 0, 0);
        }
    }

    const int rbase = blockIdx.x * 64 + rw * 16 + q * 4;
#pragma unroll
    for (int r = 0; r < 4; ++r) {
        const int orow = rbase + r;
        if (orow < N) {
            if (FC) {
#pragma unroll
                for (int c = 0; c < CTH; ++c)
                    Cf[(size_t)orow * M + (c0 + c) * 16 + m] = gacc[c][r] + bias2[(c0 + c) * 16 + m];
            } else {
                const float s = dinv[orow];
#pragma unroll
                for (int c = 0; c < CTH; ++c)
                    Ch[(size_t)orow * M + (c0 + c) * 16 + m] = (_Float16)(gacc[c][r] * s);
            }
        }
    }
}

extern "C" void kernel_launch(void* const* d_in, const int* in_sizes, int n_in,
                              void* d_out, int out_size, void* d_ws, size_t ws_size,
                              hipStream_t stream) {
    const float* x   = (const float*)d_in[0];
    const int*   ei  = (const int*)d_in[1];
    const float* W0  = (const float*)d_in[2];
    const float* b0  = (const float*)d_in[3];
    const float* W1  = (const float*)d_in[4];
    const float* b1  = (const float*)d_in[5];
    const float* W2  = (const float*)d_in[6];
    const float* b2  = (const float*)d_in[7];
    const float* fcW = (const float*)d_in[8];
    const float* fcb = (const float*)d_in[9];
    float* out = (float*)d_out;

    const int* src = ei;
    const int* dst = ei + NE;

    float* ws = (float*)d_ws;
    float* dinv     = ws;                       // [50000]
    int*   deg      = (int*)(ws + 50176);
    int*   excl     = (int*)(ws + 100352);
    int*   cursor   = (int*)(ws + 150528);
    int*   rowstart = (int*)(ws + 200704);
    int*   partials = (int*)(ws + 250880);      // [256]
    int*   csr_src  = (int*)(ws + 251136);      // [800000]
    short* w0hi = (short*)(ws + 1051392);       // [49152] shorts
    short* w0lo = (short*)(ws + 1075968);
    short* w1hi = (short*)(ws + 1100544);       // [9216] shorts
    short* w1lo = (short*)(ws + 1105152);
    short* w2hi = (short*)(ws + 1109760);
    short* w2lo = (short*)(ws + 1114368);
    short* fchi = (short*)(ws + 1118976);       // [6144] shorts
    short* fclo = (short*)(ws + 1122048);
    _Float16* hsA = (_Float16*)(ws + 1125120);  // [4.8M halves]
    _Float16* hsB = (_Float16*)(ws + 3525120);  // [4.8M halves]

    dim3 b256(256);
    const int gN = NBLK;                        // 196
    const int gE = (NE + 255) / 256;            // 3125
    const int gGem = (NN + 63) / 64;            // 782
    const int gPack = (73728 + 255) / 256;      // 288

    // ---- CSR build + dinv + weight pack ----
    zero_int_kernel<<<gN, b256, 0, stream>>>(deg, NN);
    hist_kernel<<<gE, b256, 0, stream>>>(dst, deg);
    scan1_kernel<<<gN, b256, 0, stream>>>(deg, excl, partials);
    scan3_kernel<<<gN, b256, 0, stream>>>(excl, partials, deg, rowstart, dinv, cursor);
    scatter_kernel<<<gE, b256, 0, stream>>>(src, dst, rowstart, cursor, csr_src);
    pack_all<<<gPack, b256, 0, stream>>>(W0, W1, W2, fcW, w0hi, w0lo, w1hi, w1lo,
                                         w2hi, w2lo, fchi, fclo);

    // ---- layer 0 GEMM: hs0 = (x@W0)*dinv ----
    mfma_gemm_f<KIN><<<gGem, dim3(512), 0, stream>>>(x, w0hi, w0lo, dinv, hsA, NN);

    // ---- fused: h1 = relu(gather(hs0)+b0); hs1 = (h1@W1)*dinv ----
    fused_gg<HIDD, false><<<gGem, dim3(512), 0, stream>>>(
        rowstart, deg, csr_src, dinv, (const h4*)hsA, b0, w1hi, w1lo, nullptr, hsB, nullptr, NN);

    // ---- fused: h2 = relu(gather(hs1)+b1); hs2 = (h2@W2)*dinv ----
    fused_gg<HIDD, false><<<gGem, dim3(512), 0, stream>>>(
        rowstart, deg, csr_src, dinv, (const h4*)hsB, b1, w2hi, w2lo, nullptr, hsA, nullptr, NN);

    // ---- fused: h3 = relu(gather(hs2)+b2); out = h3@fcW + fcb ----
    fused_gg<ODIM, true><<<gGem, dim3(512), 0, stream>>>(
        rowstart, deg, csr_src, dinv, (const h4*)hsA, b2, fchi, fclo, fcb, nullptr, out, NN);
}